// Round 1
// baseline (1011.128 us; speedup 1.0000x reference)
//
#include <hip/hip_runtime.h>

// GAT encoder, MI355X. Key algebraic fold: edge features only enter via the
// attention logit a_edge = (edge_attr @ edge_w + edge_b) @ lin_edge_w(+att fold)
// = edge_attr(4) @ M[l](4x4) + c0[l](4). No [E,64] edge projection ever needed.
// CSR-by-dst (built once) -> wave-per-node GAT with zero float atomics,
// fused softmax (single pass; shift-invariant) + bias + residual + LN + ReLU.

#define LRELU_SLOPE 0.2f

// ---- tiny per-layer weight folding: M[3][4][4], c0[3][4] ----
__global__ void k_smallw(const float* __restrict__ lin_edge_w, // [3][64][64]
                         const float* __restrict__ att_edge,   // [3][4][16]
                         const float* __restrict__ edge_w,     // [4][64]
                         const float* __restrict__ edge_b,     // [64]
                         float* __restrict__ Mc)               // [48] M + [12] c0
{
    __shared__ float we[3][64][4];
    int t = threadIdx.x;
    if (t < 192) {
        int l = t >> 6, k = t & 63;
        for (int h = 0; h < 4; ++h) {
            float acc = 0.f;
            #pragma unroll
            for (int c = 0; c < 16; ++c)
                acc = fmaf(lin_edge_w[l*4096 + k*64 + h*16 + c],
                           att_edge[l*64 + h*16 + c], acc);
            we[l][k][h] = acc;
        }
    }
    __syncthreads();
    if (t < 48) {
        int l = t >> 4, k4 = (t >> 2) & 3, h = t & 3;
        float acc = 0.f;
        for (int k = 0; k < 64; ++k)
            acc = fmaf(edge_w[k4*64 + k], we[l][k][h], acc);
        Mc[l*16 + k4*4 + h] = acc;
    }
    if (t >= 64 && t < 76) {
        int u = t - 64, l = u >> 2, h = u & 3;
        float acc = 0.f;
        for (int k = 0; k < 64; ++k)
            acc = fmaf(edge_b[k], we[l][k][h], acc);
        Mc[48 + l*4 + h] = acc;
    }
}

// ---- h0 = x @ node_w + node_b ----
__global__ void k_node_proj(const float* __restrict__ x, const float* __restrict__ nw,
                            const float* __restrict__ nb, float* __restrict__ h, int n_nodes)
{
    int idx = blockIdx.x * blockDim.x + threadIdx.x;
    int n = idx >> 6, j = idx & 63;
    if (n >= n_nodes) return;
    float acc = nb[j];
    #pragma unroll
    for (int k = 0; k < 8; ++k) acc = fmaf(x[n*8 + k], nw[k*64 + j], acc);
    h[(size_t)n*64 + j] = acc;
}

// ---- CSR build ----
__global__ void k_deg(const int* __restrict__ dst, int* __restrict__ deg, int E) {
    for (int e = blockIdx.x*blockDim.x + threadIdx.x; e < E; e += gridDim.x*blockDim.x)
        atomicAdd(&deg[dst[e]], 1);
}

__global__ void k_scan1(const int* __restrict__ deg, int* __restrict__ rowptr1,
                        int* __restrict__ bsum, int n) {
    __shared__ int s[1024];
    int i = blockIdx.x*1024 + threadIdx.x;
    s[threadIdx.x] = (i < n) ? deg[i] : 0;
    __syncthreads();
    for (int off = 1; off < 1024; off <<= 1) {
        int t = (threadIdx.x >= off) ? s[threadIdx.x - off] : 0;
        __syncthreads();
        s[threadIdx.x] += t;
        __syncthreads();
    }
    if (i < n) rowptr1[i] = s[threadIdx.x];           // inclusive chunk scan
    if (threadIdx.x == 1023) bsum[blockIdx.x] = s[1023];
}

__global__ void k_scan2(int* bsum, int nb) {          // nb <= 128, 1 block
    __shared__ int s[128];
    int t = threadIdx.x;
    s[t] = (t < nb) ? bsum[t] : 0;
    __syncthreads();
    for (int off = 1; off < 128; off <<= 1) {
        int v = (t >= off) ? s[t - off] : 0;
        __syncthreads();
        s[t] += v;
        __syncthreads();
    }
    if (t < nb) bsum[t] = (t == 0) ? 0 : s[t - 1];    // exclusive block offsets
}

__global__ void k_scan3(int* __restrict__ rowptr, const int* __restrict__ bsum, int n) {
    int i = blockIdx.x*1024 + threadIdx.x;
    if (i < n) rowptr[i + 1] += bsum[blockIdx.x];
    if (i == 0) rowptr[0] = 0;
}

__global__ void k_scatter(const int* __restrict__ src, const int* __restrict__ dst,
                          const int* __restrict__ rowptr, int* __restrict__ cursor,
                          int* __restrict__ csr_src, int* __restrict__ csr_aid, int E) {
    for (int e = blockIdx.x*blockDim.x + threadIdx.x; e < E; e += gridDim.x*blockDim.x) {
        int d = dst[e];
        int slot = rowptr[d] + atomicAdd(&cursor[d], 1);
        csr_src[slot] = src[e];
        csr_aid[slot] = e;
    }
}

__global__ void k_reorder(const int* __restrict__ csr_aid, const float4* __restrict__ edge_attr,
                          float4* __restrict__ ea_csr, int E) {
    for (int s = blockIdx.x*blockDim.x + threadIdx.x; s < E; s += gridDim.x*blockDim.x)
        ea_csr[s] = edge_attr[csr_aid[s]];
}

__global__ void k_eamean(const int* __restrict__ rowptr, const float4* __restrict__ ea_csr,
                         float4* __restrict__ ea_mean, int n) {
    int i = blockIdx.x*blockDim.x + threadIdx.x;
    if (i >= n) return;
    int b = rowptr[i], e = rowptr[i + 1];
    float sx = 0.f, sy = 0.f, sz = 0.f, sw = 0.f;
    for (int s = b; s < e; ++s) {
        float4 v = ea_csr[s];
        sx += v.x; sy += v.y; sz += v.z; sw += v.w;
    }
    float inv = (e > b) ? 1.f / (float)(e - b) : 0.f;  // deg=0 -> e_mean = 0
    ea_mean[i] = make_float4(sx*inv, sy*inv, sz*inv, sw*inv);
}

// ---- per layer: xs = h @ lin_w[l]; fused a_src/a_dst head reductions ----
__global__ __launch_bounds__(256) void k_proj(const float* __restrict__ h,
        const float* __restrict__ lw,   // lin_w + l*4096
        const float* __restrict__ asw,  // att_src + l*64
        const float* __restrict__ adw,  // att_dst + l*64
        float* __restrict__ xs, float* __restrict__ a_src4, float* __restrict__ a_dst4,
        int n_nodes)
{
    __shared__ float W[4096];
    for (int i = threadIdx.x; i < 4096; i += 256) W[i] = lw[i];
    __syncthreads();
    int lane = threadIdx.x & 63, wid = threadIdx.x >> 6;
    float as_w = asw[lane], ad_w = adw[lane];
    for (int n = blockIdx.x*4 + wid; n < n_nodes; n += gridDim.x*4) {
        const float* hrow = h + (size_t)n*64;
        float acc = 0.f;
        #pragma unroll
        for (int k = 0; k < 64; ++k) acc = fmaf(hrow[k], W[k*64 + lane], acc);
        xs[(size_t)n*64 + lane] = acc;
        float ps = acc * as_w, pd = acc * ad_w;
        #pragma unroll
        for (int o = 1; o < 16; o <<= 1) {
            ps += __shfl_xor(ps, o, 16);
            pd += __shfl_xor(pd, o, 16);
        }
        if ((lane & 15) == 0) {
            a_src4[n*4 + (lane >> 4)] = ps;
            a_dst4[n*4 + (lane >> 4)] = pd;
        }
    }
}

// ---- per layer: wave-per-node GAT + bias + residual + LN + ReLU (in-place h) ----
__global__ __launch_bounds__(256) void k_gat(const float* __restrict__ xs,
        const float* __restrict__ a_src4, const float* __restrict__ a_dst4,
        const int* __restrict__ rowptr, const int* __restrict__ csr_src,
        const float4* __restrict__ ea_csr, const float4* __restrict__ ea_mean,
        const float* __restrict__ Mc,   // M + l*16
        const float* __restrict__ c0,   // c0 + l*4
        const float* __restrict__ bias, const float* __restrict__ lng,
        const float* __restrict__ lnb, float* __restrict__ hio, int n_nodes)
{
    int n = blockIdx.x*4 + (threadIdx.x >> 6);
    if (n >= n_nodes) return;
    int lane = threadIdx.x & 63, hh = lane >> 4;
    float m0 = Mc[hh], m1 = Mc[4 + hh], m2 = Mc[8 + hh], m3 = Mc[12 + hh];
    float ch = c0[hh];
    float adst = a_dst4[n*4 + hh];
    int b = rowptr[n], e = rowptr[n + 1];
    // self-loop (edge feature = per-dst mean; zero if deg==0)
    float4 eam = ea_mean[n];
    float ael = (e > b) ? fmaf(eam.x, m0, fmaf(eam.y, m1, fmaf(eam.z, m2, fmaf(eam.w, m3, ch))))
                        : 0.f;
    float al = a_src4[n*4 + hh] + adst + ael;
    al = (al > 0.f) ? al : LRELU_SLOPE * al;
    float ex = __expf(al);                  // softmax is shift-invariant; |alpha| small
    float den = ex;
    float acc = ex * xs[(size_t)n*64 + lane];
    for (int s = b; s < e; ++s) {
        int sn = csr_src[s];
        float4 ea = ea_csr[s];
        float ae = fmaf(ea.x, m0, fmaf(ea.y, m1, fmaf(ea.z, m2, fmaf(ea.w, m3, ch))));
        float a = a_src4[sn*4 + hh] + adst + ae;
        a = (a > 0.f) ? a : LRELU_SLOPE * a;
        float x = __expf(a);
        den += x;
        acc = fmaf(x, xs[(size_t)sn*64 + lane], acc);
    }
    float out = acc / (den + 1e-16f) + bias[lane] + hio[(size_t)n*64 + lane];
    // LayerNorm across 64 lanes + ReLU
    float s1 = out;
    #pragma unroll
    for (int o = 1; o < 64; o <<= 1) s1 += __shfl_xor(s1, o, 64);
    float mu = s1 * 0.015625f;
    float d = out - mu;
    float s2 = d * d;
    #pragma unroll
    for (int o = 1; o < 64; o <<= 1) s2 += __shfl_xor(s2, o, 64);
    float y = d * rsqrtf(s2 * 0.015625f + 1e-5f) * lng[lane] + lnb[lane];
    hio[(size_t)n*64 + lane] = (y > 0.f) ? y : 0.f;
}

extern "C" void kernel_launch(void* const* d_in, const int* in_sizes, int n_in,
                              void* d_out, int out_size, void* d_ws, size_t ws_size,
                              hipStream_t stream) {
    const float* x          = (const float*)d_in[0];
    const int*   ei         = (const int*)d_in[1];
    const float* edge_attr  = (const float*)d_in[2];
    const float* node_w     = (const float*)d_in[3];
    const float* node_b     = (const float*)d_in[4];
    const float* edge_w     = (const float*)d_in[5];
    const float* edge_b     = (const float*)d_in[6];
    const float* lin_w      = (const float*)d_in[7];
    const float* lin_edge_w = (const float*)d_in[8];
    const float* att_src    = (const float*)d_in[9];
    const float* att_dst    = (const float*)d_in[10];
    const float* att_edge   = (const float*)d_in[11];
    const float* gat_bias   = (const float*)d_in[12];
    const float* ln_g       = (const float*)d_in[13];
    const float* ln_b       = (const float*)d_in[14];

    int NN = in_sizes[0] / 8;
    int E  = in_sizes[1] / 2;
    const int* src = ei;
    const int* dst = ei + E;
    float* h = (float*)d_out;

    char* wsp = (char*)d_ws;
    size_t off = 0;
    auto alloc = [&](size_t bytes) -> void* {
        off = (off + 255) & ~(size_t)255;
        void* p = wsp + off;
        off += bytes;
        return p;
    };
    float*  xs      = (float*)alloc((size_t)NN * 64 * 4);
    float*  a_src4  = (float*)alloc((size_t)NN * 4 * 4);
    float*  a_dst4  = (float*)alloc((size_t)NN * 4 * 4);
    float4* ea_csr  = (float4*)alloc((size_t)E * 16);
    float4* ea_mean = (float4*)alloc((size_t)NN * 16);
    int*    rowptr  = (int*)alloc((size_t)(NN + 1) * 4);
    int*    degc    = (int*)alloc((size_t)NN * 4);
    int*    csr_src = (int*)alloc((size_t)E * 4);
    int*    csr_aid = (int*)alloc((size_t)E * 4);
    int*    bsum    = (int*)alloc(512);
    float*  Mc      = (float*)alloc(256);

    hipMemsetAsync(degc, 0, (size_t)NN * 4, stream);
    k_smallw<<<1, 256, 0, stream>>>(lin_edge_w, att_edge, edge_w, edge_b, Mc);
    k_node_proj<<<(NN*64 + 255) / 256, 256, 0, stream>>>(x, node_w, node_b, h, NN);
    k_deg<<<2048, 256, 0, stream>>>(dst, degc, E);
    int nb = (NN + 1023) / 1024;
    k_scan1<<<nb, 1024, 0, stream>>>(degc, rowptr + 1, bsum, NN);
    k_scan2<<<1, 128, 0, stream>>>(bsum, nb);
    k_scan3<<<nb, 1024, 0, stream>>>(rowptr, bsum, NN);
    hipMemsetAsync(degc, 0, (size_t)NN * 4, stream);   // reuse as scatter cursor
    k_scatter<<<2048, 256, 0, stream>>>(src, dst, rowptr, degc, csr_src, csr_aid, E);
    k_reorder<<<2048, 256, 0, stream>>>(csr_aid, (const float4*)edge_attr, ea_csr, E);
    k_eamean<<<(NN + 255) / 256, 256, 0, stream>>>(rowptr, ea_csr, ea_mean, NN);

    for (int l = 0; l < 3; ++l) {
        k_proj<<<2048, 256, 0, stream>>>(h, lin_w + l*4096, att_src + l*64, att_dst + l*64,
                                         xs, a_src4, a_dst4, NN);
        k_gat<<<(NN + 3) / 4, 256, 0, stream>>>(xs, a_src4, a_dst4, rowptr, csr_src,
                                                ea_csr, ea_mean, Mc + l*16, Mc + 48 + l*4,
                                                gat_bias + l*64, ln_g + l*64, ln_b + l*64,
                                                h, NN);
    }
}

// Round 2
// 638.776 us; speedup vs baseline: 1.5829x; 1.5829x over previous
//
#include <hip/hip_runtime.h>

// GAT encoder, MI355X. Algebraic fold: edge features only enter via the logit
// a_edge = edge_attr(4) @ M[l](4x4) + c0[l](4)  (edge proj folded through att_edge).
// CSR-by-dst (built once), wave-per-node GAT:
//   phase A: 16 edges x 4 heads logits across 64 lanes, ONE wave exp per chunk
//   phase B: 8-edge gathers, 8 lanes x dwordx4 of bf16 xs row (128B = 1 line)
// Messages in bf16 (xs stored as ushort), logits fp32. Fused softmax (shift-
// invariant, no max pass) + bias + residual + LayerNorm + ReLU.

#define LRELU_SLOPE 0.2f

__device__ __forceinline__ ushort f2bf(float x) {
    unsigned int b = __float_as_uint(x);
    return (ushort)((b + 0x7fffu + ((b >> 16) & 1u)) >> 16);   // RNE
}
__device__ __forceinline__ float bf_lo(unsigned int v) { return __uint_as_float(v << 16); }
__device__ __forceinline__ float bf_hi(unsigned int v) { return __uint_as_float(v & 0xffff0000u); }

// ---- tiny per-layer weight folding: M[3][4][4], c0[3][4] ----
__global__ void k_smallw(const float* __restrict__ lin_edge_w, // [3][64][64]
                         const float* __restrict__ att_edge,   // [3][4][16]
                         const float* __restrict__ edge_w,     // [4][64]
                         const float* __restrict__ edge_b,     // [64]
                         float* __restrict__ Mc)               // [48] M + [12] c0
{
    __shared__ float we[3][64][4];
    int t = threadIdx.x;
    if (t < 192) {
        int l = t >> 6, k = t & 63;
        for (int h = 0; h < 4; ++h) {
            float acc = 0.f;
            #pragma unroll
            for (int c = 0; c < 16; ++c)
                acc = fmaf(lin_edge_w[l*4096 + k*64 + h*16 + c],
                           att_edge[l*64 + h*16 + c], acc);
            we[l][k][h] = acc;
        }
    }
    __syncthreads();
    if (t < 48) {
        int l = t >> 4, k4 = (t >> 2) & 3, h = t & 3;
        float acc = 0.f;
        for (int k = 0; k < 64; ++k)
            acc = fmaf(edge_w[k4*64 + k], we[l][k][h], acc);
        Mc[l*16 + k4*4 + h] = acc;
    }
    if (t >= 64 && t < 76) {
        int u = t - 64, l = u >> 2, h = u & 3;
        float acc = 0.f;
        for (int k = 0; k < 64; ++k)
            acc = fmaf(edge_b[k], we[l][k][h], acc);
        Mc[48 + l*4 + h] = acc;
    }
}

// ---- h0 = x @ node_w + node_b ----
__global__ void k_node_proj(const float* __restrict__ x, const float* __restrict__ nw,
                            const float* __restrict__ nb, float* __restrict__ h, int n_nodes)
{
    int idx = blockIdx.x * blockDim.x + threadIdx.x;
    int n = idx >> 6, j = idx & 63;
    if (n >= n_nodes) return;
    float acc = nb[j];
    #pragma unroll
    for (int k = 0; k < 8; ++k) acc = fmaf(x[n*8 + k], nw[k*64 + j], acc);
    h[(size_t)n*64 + j] = acc;
}

// ---- CSR build ----
__global__ void k_deg(const int* __restrict__ dst, int* __restrict__ deg, int E) {
    for (int e = blockIdx.x*blockDim.x + threadIdx.x; e < E; e += gridDim.x*blockDim.x)
        atomicAdd(&deg[dst[e]], 1);
}

__global__ void k_scan1(const int* __restrict__ deg, int* __restrict__ rowptr1,
                        int* __restrict__ bsum, int n) {
    __shared__ int s[1024];
    int i = blockIdx.x*1024 + threadIdx.x;
    s[threadIdx.x] = (i < n) ? deg[i] : 0;
    __syncthreads();
    for (int off = 1; off < 1024; off <<= 1) {
        int t = (threadIdx.x >= off) ? s[threadIdx.x - off] : 0;
        __syncthreads();
        s[threadIdx.x] += t;
        __syncthreads();
    }
    if (i < n) rowptr1[i] = s[threadIdx.x];           // inclusive chunk scan
    if (threadIdx.x == 1023) bsum[blockIdx.x] = s[1023];
}

__global__ void k_scan2(int* bsum, int nb) {          // nb <= 128, 1 block
    __shared__ int s[128];
    int t = threadIdx.x;
    s[t] = (t < nb) ? bsum[t] : 0;
    __syncthreads();
    for (int off = 1; off < 128; off <<= 1) {
        int v = (t >= off) ? s[t - off] : 0;
        __syncthreads();
        s[t] += v;
        __syncthreads();
    }
    if (t < nb) bsum[t] = (t == 0) ? 0 : s[t - 1];    // exclusive block offsets
}

__global__ void k_scan3(int* __restrict__ rowptr, const int* __restrict__ bsum, int n) {
    int i = blockIdx.x*1024 + threadIdx.x;
    if (i < n) rowptr[i + 1] += bsum[blockIdx.x];
    if (i == 0) rowptr[0] = 0;
}

// scatter src index AND edge_attr directly into CSR order (reorder fused)
__global__ void k_scatter(const int* __restrict__ src, const int* __restrict__ dst,
                          const float4* __restrict__ edge_attr,
                          const int* __restrict__ rowptr, int* __restrict__ cursor,
                          int* __restrict__ csr_src, float4* __restrict__ ea_csr, int E) {
    for (int e = blockIdx.x*blockDim.x + threadIdx.x; e < E; e += gridDim.x*blockDim.x) {
        int d = dst[e];
        int slot = rowptr[d] + atomicAdd(&cursor[d], 1);
        csr_src[slot] = src[e];
        ea_csr[slot] = edge_attr[e];
    }
}

__global__ void k_eamean(const int* __restrict__ rowptr, const float4* __restrict__ ea_csr,
                         float4* __restrict__ ea_mean, int n) {
    int i = blockIdx.x*blockDim.x + threadIdx.x;
    if (i >= n) return;
    int b = rowptr[i], e = rowptr[i + 1];
    float sx = 0.f, sy = 0.f, sz = 0.f, sw = 0.f;
    for (int s = b; s < e; ++s) {
        float4 v = ea_csr[s];
        sx += v.x; sy += v.y; sz += v.z; sw += v.w;
    }
    float inv = (e > b) ? 1.f / (float)(e - b) : 0.f;  // deg=0 -> e_mean = 0
    ea_mean[i] = make_float4(sx*inv, sy*inv, sz*inv, sw*inv);
}

// ---- per layer: xs = h @ lin_w[l] (bf16 out); fused a_src/a_dst reductions ----
__global__ __launch_bounds__(256) void k_proj(const float* __restrict__ h,
        const float* __restrict__ lw,   // lin_w + l*4096
        const float* __restrict__ asw,  // att_src + l*64
        const float* __restrict__ adw,  // att_dst + l*64
        ushort* __restrict__ xs2, float* __restrict__ a_src4, float* __restrict__ a_dst4,
        int n_nodes)
{
    __shared__ float W[4096];
    for (int i = threadIdx.x; i < 4096; i += 256) W[i] = lw[i];
    __syncthreads();
    int lane = threadIdx.x & 63, wid = threadIdx.x >> 6;
    float as_w = asw[lane], ad_w = adw[lane];
    for (int n = blockIdx.x*4 + wid; n < n_nodes; n += gridDim.x*4) {
        const float* hrow = h + (size_t)n*64;
        float acc = 0.f;
        #pragma unroll
        for (int k = 0; k < 64; ++k) acc = fmaf(hrow[k], W[k*64 + lane], acc);
        xs2[(size_t)n*64 + lane] = f2bf(acc);
        float ps = acc * as_w, pd = acc * ad_w;
        #pragma unroll
        for (int o = 1; o < 16; o <<= 1) {
            ps += __shfl_xor(ps, o, 16);
            pd += __shfl_xor(pd, o, 16);
        }
        if ((lane & 15) == 0) {
            a_src4[n*4 + (lane >> 4)] = ps;
            a_dst4[n*4 + (lane >> 4)] = pd;
        }
    }
}

// ---- per layer: wave-per-node GAT + bias + residual + LN + ReLU (in-place h) ----
__global__ __launch_bounds__(256) void k_gat(const ushort* __restrict__ xs2, // [N][64] bf16
        const float* __restrict__ a_src4, const float* __restrict__ a_dst4,
        const int* __restrict__ rowptr, const int* __restrict__ csr_src,
        const float4* __restrict__ ea_csr, const float4* __restrict__ ea_mean,
        const float* __restrict__ Mc,   // M + l*16
        const float* __restrict__ c0,   // c0 + l*4
        const float* __restrict__ bias, const float* __restrict__ lng,
        const float* __restrict__ lnb, float* __restrict__ hio, int n_nodes)
{
    int n = blockIdx.x*4 + (threadIdx.x >> 6);
    if (n >= n_nodes) return;
    int lane = threadIdx.x & 63;
    int hA  = lane & 3;        // head in logit phase (lane = e*4 + h)
    int k8  = lane & 7;        // channel-octet index in gather phase
    int hB  = k8 >> 1;         // head owning channels 8*k8..8*k8+7
    int grp = lane >> 3;       // edge subgroup 0..7 in gather phase
    // phase-A per-head constants
    float m0A = Mc[hA], m1A = Mc[4+hA], m2A = Mc[8+hA], m3A = Mc[12+hA];
    float chA = c0[hA];
    float adA = a_dst4[n*4 + hA];
    int rb = rowptr[n], re = rowptr[n + 1];

    float den = 0.f;
    float a0=0.f,a1=0.f,a2=0.f,a3=0.f,a4=0.f,a5=0.f,a6=0.f,a7=0.f;

    for (int b = rb; b < re; b += 16) {
        // ---- phase A: logits for 16 edges x 4 heads across 64 lanes ----
        int s = b + (lane >> 2);
        bool valid = s < re;
        int sc = valid ? s : (re - 1);
        int sn = csr_src[sc];
        float4 ea = ea_csr[sc];
        float al = fmaf(ea.x, m0A, fmaf(ea.y, m1A, fmaf(ea.z, m2A, fmaf(ea.w, m3A, chA))))
                 + a_src4[sn*4 + hA] + adA;
        al = (al > 0.f) ? al : LRELU_SLOPE * al;
        float ev = valid ? __expf(al) : 0.f;
        float ds = ev;
        ds += __shfl_xor(ds, 4);  ds += __shfl_xor(ds, 8);
        ds += __shfl_xor(ds, 16); ds += __shfl_xor(ds, 32);
        den += ds;                                   // replicated per head hA
        // ---- phase B: gather+accumulate, 8 edges per iteration ----
        #pragma unroll
        for (int half = 0; half < 2; ++half) {
            if (b + half*8 >= re) break;             // wave-uniform
            int e_loc = half*8 + grp;
            int snb = __shfl(sn, e_loc << 2);
            float w  = __shfl(ev, (e_loc << 2) + hB);
            unsigned int idx = ((unsigned int)snb << 3) + (unsigned int)k8;
            uint4 v = ((const uint4*)xs2)[idx];
            a0 = fmaf(bf_lo(v.x), w, a0); a1 = fmaf(bf_hi(v.x), w, a1);
            a2 = fmaf(bf_lo(v.y), w, a2); a3 = fmaf(bf_hi(v.y), w, a3);
            a4 = fmaf(bf_lo(v.z), w, a4); a5 = fmaf(bf_hi(v.z), w, a5);
            a6 = fmaf(bf_lo(v.w), w, a6); a7 = fmaf(bf_hi(v.w), w, a7);
        }
    }
    // cross-group reduction (groups 0..7 each hold partial sums)
    #define XR(A) A += __shfl_xor(A, 8); A += __shfl_xor(A, 16); A += __shfl_xor(A, 32);
    XR(a0) XR(a1) XR(a2) XR(a3) XR(a4) XR(a5) XR(a6) XR(a7)
    #undef XR
    // self-loop (edge feature = per-dst mean; zero if deg==0), head hB per lane
    float m0B = Mc[hB], m1B = Mc[4+hB], m2B = Mc[8+hB], m3B = Mc[12+hB];
    float4 eam = ea_mean[n];
    float ael = (re > rb)
        ? fmaf(eam.x, m0B, fmaf(eam.y, m1B, fmaf(eam.z, m2B, fmaf(eam.w, m3B, c0[hB]))))
        : 0.f;
    float alS = a_src4[n*4 + hB] + a_dst4[n*4 + hB] + ael;
    alS = (alS > 0.f) ? alS : LRELU_SLOPE * alS;
    float evS = __expf(alS);
    float denF = __shfl(den, hB) + evS;
    unsigned int idxS = ((unsigned int)n << 3) + (unsigned int)k8;
    uint4 vs = ((const uint4*)xs2)[idxS];
    a0 = fmaf(bf_lo(vs.x), evS, a0); a1 = fmaf(bf_hi(vs.x), evS, a1);
    a2 = fmaf(bf_lo(vs.y), evS, a2); a3 = fmaf(bf_hi(vs.y), evS, a3);
    a4 = fmaf(bf_lo(vs.z), evS, a4); a5 = fmaf(bf_hi(vs.z), evS, a5);
    a6 = fmaf(bf_lo(vs.w), evS, a7*0.f + a6); a7 = fmaf(bf_hi(vs.w), evS, a7);
    // epilogue: /den + bias + residual, LayerNorm over 64 ch, ReLU
    float inv = 1.f / (denF + 1e-16f);
    int cb = k8 * 8;
    const float4* hr = (const float4*)(hio + (size_t)n*64 + cb);
    float4 r0 = hr[0], r1 = hr[1];
    const float4* bp = (const float4*)(bias + cb);
    float4 b0 = bp[0], b1 = bp[1];
    float o0 = a0*inv + b0.x + r0.x, o1 = a1*inv + b0.y + r0.y;
    float o2 = a2*inv + b0.z + r0.z, o3 = a3*inv + b0.w + r0.w;
    float o4 = a4*inv + b1.x + r1.x, o5 = a5*inv + b1.y + r1.y;
    float o6 = a6*inv + b1.z + r1.z, o7 = a7*inv + b1.w + r1.w;
    float s1 = o0+o1+o2+o3+o4+o5+o6+o7;
    s1 += __shfl_xor(s1, 1); s1 += __shfl_xor(s1, 2); s1 += __shfl_xor(s1, 4);
    float mu = s1 * 0.015625f;
    float d0=o0-mu,d1=o1-mu,d2=o2-mu,d3=o3-mu,d4=o4-mu,d5=o5-mu,d6=o6-mu,d7=o7-mu;
    float s2 = d0*d0+d1*d1+d2*d2+d3*d3+d4*d4+d5*d5+d6*d6+d7*d7;
    s2 += __shfl_xor(s2, 1); s2 += __shfl_xor(s2, 2); s2 += __shfl_xor(s2, 4);
    float rs = rsqrtf(s2 * 0.015625f + 1e-5f);
    const float4* gp = (const float4*)(lng + cb);
    const float4* zp = (const float4*)(lnb + cb);
    float4 g0 = gp[0], g1 = gp[1], z0 = zp[0], z1 = zp[1];
    float y0 = fmaxf(d0*rs*g0.x + z0.x, 0.f), y1 = fmaxf(d1*rs*g0.y + z0.y, 0.f);
    float y2 = fmaxf(d2*rs*g0.z + z0.z, 0.f), y3 = fmaxf(d3*rs*g0.w + z0.w, 0.f);
    float y4 = fmaxf(d4*rs*g1.x + z1.x, 0.f), y5 = fmaxf(d5*rs*g1.y + z1.y, 0.f);
    float y6 = fmaxf(d6*rs*g1.z + z1.z, 0.f), y7 = fmaxf(d7*rs*g1.w + z1.w, 0.f);
    if (lane < 8) {
        float4* outp = (float4*)(hio + (size_t)n*64 + cb);
        outp[0] = make_float4(y0, y1, y2, y3);
        outp[1] = make_float4(y4, y5, y6, y7);
    }
}

extern "C" void kernel_launch(void* const* d_in, const int* in_sizes, int n_in,
                              void* d_out, int out_size, void* d_ws, size_t ws_size,
                              hipStream_t stream) {
    const float* x          = (const float*)d_in[0];
    const int*   ei         = (const int*)d_in[1];
    const float* edge_attr  = (const float*)d_in[2];
    const float* node_w     = (const float*)d_in[3];
    const float* node_b     = (const float*)d_in[4];
    const float* edge_w     = (const float*)d_in[5];
    const float* edge_b     = (const float*)d_in[6];
    const float* lin_w      = (const float*)d_in[7];
    const float* lin_edge_w = (const float*)d_in[8];
    const float* att_src    = (const float*)d_in[9];
    const float* att_dst    = (const float*)d_in[10];
    const float* att_edge   = (const float*)d_in[11];
    const float* gat_bias   = (const float*)d_in[12];
    const float* ln_g       = (const float*)d_in[13];
    const float* ln_b       = (const float*)d_in[14];

    int NN = in_sizes[0] / 8;
    int E  = in_sizes[1] / 2;
    const int* src = ei;
    const int* dst = ei + E;
    float* h = (float*)d_out;

    char* wsp = (char*)d_ws;
    size_t off = 0;
    auto alloc = [&](size_t bytes) -> void* {
        off = (off + 255) & ~(size_t)255;
        void* p = wsp + off;
        off += bytes;
        return p;
    };
    ushort* xs2     = (ushort*)alloc((size_t)NN * 64 * 2);
    float*  a_src4  = (float*)alloc((size_t)NN * 4 * 4);
    float*  a_dst4  = (float*)alloc((size_t)NN * 4 * 4);
    float4* ea_csr  = (float4*)alloc((size_t)E * 16);
    float4* ea_mean = (float4*)alloc((size_t)NN * 16);
    int*    rowptr  = (int*)alloc((size_t)(NN + 1) * 4);
    int*    degc    = (int*)alloc((size_t)NN * 4);
    int*    csr_src = (int*)alloc((size_t)E * 4);
    int*    bsum    = (int*)alloc(512);
    float*  Mc      = (float*)alloc(256);

    hipMemsetAsync(degc, 0, (size_t)NN * 4, stream);
    k_smallw<<<1, 256, 0, stream>>>(lin_edge_w, att_edge, edge_w, edge_b, Mc);
    k_node_proj<<<(NN*64 + 255) / 256, 256, 0, stream>>>(x, node_w, node_b, h, NN);
    k_deg<<<2048, 256, 0, stream>>>(dst, degc, E);
    int nb = (NN + 1023) / 1024;
    k_scan1<<<nb, 1024, 0, stream>>>(degc, rowptr + 1, bsum, NN);
    k_scan2<<<1, 128, 0, stream>>>(bsum, nb);
    k_scan3<<<nb, 1024, 0, stream>>>(rowptr, bsum, NN);
    hipMemsetAsync(degc, 0, (size_t)NN * 4, stream);   // reuse as scatter cursor
    k_scatter<<<2048, 256, 0, stream>>>(src, dst, (const float4*)edge_attr,
                                        rowptr, degc, csr_src, ea_csr, E);
    k_eamean<<<(NN + 255) / 256, 256, 0, stream>>>(rowptr, ea_csr, ea_mean, NN);

    for (int l = 0; l < 3; ++l) {
        k_proj<<<2048, 256, 0, stream>>>(h, lin_w + l*4096, att_src + l*64, att_dst + l*64,
                                         xs2, a_src4, a_dst4, NN);
        k_gat<<<(NN + 3) / 4, 256, 0, stream>>>(xs2, a_src4, a_dst4, rowptr, csr_src,
                                                ea_csr, ea_mean, Mc + l*16, Mc + 48 + l*4,
                                                gat_bias + l*64, ln_g + l*64, ln_b + l*64,
                                                h, NN);
    }
}

// Round 3
// 598.872 us; speedup vs baseline: 1.6884x; 1.0666x over previous
//
#include <hip/hip_runtime.h>

// GAT encoder, MI355X. Algebraic fold: edge features only enter via the logit
// a_edge = edge_attr(4) @ M[l](4x4) + c0[l](4)  (edge proj folded through att_edge).
// CSR-by-dst built with rank-from-histogram (no atomics in scatter), edges stored
// as ONE fused 16B record {src, ea.xy bf16, ea.zw bf16, -}. Wave-per-node GAT:
//   phase A: 16 edges x 4 heads logits across 64 lanes, ONE wave exp per chunk
//   phase B: 8-edge gathers, 8 lanes x dwordx4 of bf16 xs row (128B = 1 line)
// Messages bf16, logits fp32. Fused softmax (shift-invariant) + bias + residual
// + LayerNorm + ReLU.

#define LRELU_SLOPE 0.2f

__device__ __forceinline__ ushort f2bf(float x) {
    unsigned int b = __float_as_uint(x);
    return (ushort)((b + 0x7fffu + ((b >> 16) & 1u)) >> 16);   // RNE
}
__device__ __forceinline__ unsigned int pack2bf(float a, float b) {
    return (unsigned int)f2bf(a) | ((unsigned int)f2bf(b) << 16);
}
__device__ __forceinline__ float bf_lo(unsigned int v) { return __uint_as_float(v << 16); }
__device__ __forceinline__ float bf_hi(unsigned int v) { return __uint_as_float(v & 0xffff0000u); }

// ---- tiny per-layer weight folding: M[3][4][4], c0[3][4] ----
__global__ void k_smallw(const float* __restrict__ lin_edge_w, // [3][64][64]
                         const float* __restrict__ att_edge,   // [3][4][16]
                         const float* __restrict__ edge_w,     // [4][64]
                         const float* __restrict__ edge_b,     // [64]
                         float* __restrict__ Mc)               // [48] M + [12] c0
{
    __shared__ float we[3][64][4];
    int t = threadIdx.x;
    if (t < 192) {
        int l = t >> 6, k = t & 63;
        for (int h = 0; h < 4; ++h) {
            float acc = 0.f;
            #pragma unroll
            for (int c = 0; c < 16; ++c)
                acc = fmaf(lin_edge_w[l*4096 + k*64 + h*16 + c],
                           att_edge[l*64 + h*16 + c], acc);
            we[l][k][h] = acc;
        }
    }
    __syncthreads();
    if (t < 48) {
        int l = t >> 4, k4 = (t >> 2) & 3, h = t & 3;
        float acc = 0.f;
        for (int k = 0; k < 64; ++k)
            acc = fmaf(edge_w[k4*64 + k], we[l][k][h], acc);
        Mc[l*16 + k4*4 + h] = acc;
    }
    if (t >= 64 && t < 76) {
        int u = t - 64, l = u >> 2, h = u & 3;
        float acc = 0.f;
        for (int k = 0; k < 64; ++k)
            acc = fmaf(edge_b[k], we[l][k][h], acc);
        Mc[48 + l*4 + h] = acc;
    }
}

// ---- h0 = x @ node_w + node_b ----
__global__ void k_node_proj(const float* __restrict__ x, const float* __restrict__ nw,
                            const float* __restrict__ nb, float* __restrict__ h, int n_nodes)
{
    int idx = blockIdx.x * blockDim.x + threadIdx.x;
    int n = idx >> 6, j = idx & 63;
    if (n >= n_nodes) return;
    float acc = nb[j];
    #pragma unroll
    for (int k = 0; k < 8; ++k) acc = fmaf(x[n*8 + k], nw[k*64 + j], acc);
    h[(size_t)n*64 + j] = acc;
}

// ---- CSR build: histogram + per-edge rank (rank = old count) ----
__global__ void k_deg(const int* __restrict__ dst, int* __restrict__ deg,
                      int* __restrict__ rank, int E) {
    for (int e = blockIdx.x*blockDim.x + threadIdx.x; e < E; e += gridDim.x*blockDim.x)
        rank[e] = atomicAdd(&deg[dst[e]], 1);
}

__global__ void k_scan1(const int* __restrict__ deg, int* __restrict__ rowptr1,
                        int* __restrict__ bsum, int n) {
    __shared__ int s[1024];
    int i = blockIdx.x*1024 + threadIdx.x;
    s[threadIdx.x] = (i < n) ? deg[i] : 0;
    __syncthreads();
    for (int off = 1; off < 1024; off <<= 1) {
        int t = (threadIdx.x >= off) ? s[threadIdx.x - off] : 0;
        __syncthreads();
        s[threadIdx.x] += t;
        __syncthreads();
    }
    if (i < n) rowptr1[i] = s[threadIdx.x];           // inclusive chunk scan
    if (threadIdx.x == 1023) bsum[blockIdx.x] = s[1023];
}

__global__ void k_scan2(int* bsum, int nb) {          // nb <= 128, 1 block
    __shared__ int s[128];
    int t = threadIdx.x;
    s[t] = (t < nb) ? bsum[t] : 0;
    __syncthreads();
    for (int off = 1; off < 128; off <<= 1) {
        int v = (t >= off) ? s[t - off] : 0;
        __syncthreads();
        s[t] += v;
        __syncthreads();
    }
    if (t < nb) bsum[t] = (t == 0) ? 0 : s[t - 1];    // exclusive block offsets
}

__global__ void k_scan3(int* __restrict__ rowptr, const int* __restrict__ bsum, int n) {
    int i = blockIdx.x*1024 + threadIdx.x;
    if (i < n) rowptr[i + 1] += bsum[blockIdx.x];
    if (i == 0) rowptr[0] = 0;
}

// one fused 16B record per edge, single random store, no atomics
__global__ void k_scatter(const int* __restrict__ src, const int* __restrict__ dst,
                          const int* __restrict__ rank, const float4* __restrict__ edge_attr,
                          const int* __restrict__ rowptr, uint4* __restrict__ recs, int E) {
    for (int e = blockIdx.x*blockDim.x + threadIdx.x; e < E; e += gridDim.x*blockDim.x) {
        int d = dst[e];
        int slot = rowptr[d] + rank[e];
        float4 ea = edge_attr[e];
        uint4 r;
        r.x = (unsigned int)src[e];
        r.y = pack2bf(ea.x, ea.y);
        r.z = pack2bf(ea.z, ea.w);
        r.w = 0u;
        recs[slot] = r;
    }
}

__global__ void k_eamean(const int* __restrict__ rowptr, const uint4* __restrict__ recs,
                         float4* __restrict__ ea_mean, int n) {
    int i = blockIdx.x*blockDim.x + threadIdx.x;
    if (i >= n) return;
    int b = rowptr[i], e = rowptr[i + 1];
    float sx = 0.f, sy = 0.f, sz = 0.f, sw = 0.f;
    for (int s = b; s < e; ++s) {
        uint4 r = recs[s];
        sx += bf_lo(r.y); sy += bf_hi(r.y); sz += bf_lo(r.z); sw += bf_hi(r.z);
    }
    float inv = (e > b) ? 1.f / (float)(e - b) : 0.f;  // deg=0 -> e_mean = 0
    ea_mean[i] = make_float4(sx*inv, sy*inv, sz*inv, sw*inv);
}

// ---- per layer: xs = h @ lin_w[l] (bf16 out); fused a_src/a_dst reductions ----
__global__ __launch_bounds__(256) void k_proj(const float* __restrict__ h,
        const float* __restrict__ lw,   // lin_w + l*4096
        const float* __restrict__ asw,  // att_src + l*64
        const float* __restrict__ adw,  // att_dst + l*64
        ushort* __restrict__ xs2, float* __restrict__ a_src4, float* __restrict__ a_dst4,
        int n_nodes)
{
    __shared__ float W[4096];
    for (int i = threadIdx.x; i < 4096; i += 256) W[i] = lw[i];
    __syncthreads();
    int lane = threadIdx.x & 63, wid = threadIdx.x >> 6;
    float as_w = asw[lane], ad_w = adw[lane];
    for (int n = blockIdx.x*4 + wid; n < n_nodes; n += gridDim.x*4) {
        const float4* h4 = (const float4*)(h + (size_t)n*64);
        float4 hv[16];
        #pragma unroll
        for (int i = 0; i < 16; ++i) hv[i] = h4[i];     // 16 broadcast dwordx4
        float acc = 0.f;
        #pragma unroll
        for (int i = 0; i < 16; ++i) {
            acc = fmaf(hv[i].x, W[(i*4+0)*64 + lane], acc);
            acc = fmaf(hv[i].y, W[(i*4+1)*64 + lane], acc);
            acc = fmaf(hv[i].z, W[(i*4+2)*64 + lane], acc);
            acc = fmaf(hv[i].w, W[(i*4+3)*64 + lane], acc);
        }
        xs2[(size_t)n*64 + lane] = f2bf(acc);
        float ps = acc * as_w, pd = acc * ad_w;
        #pragma unroll
        for (int o = 1; o < 16; o <<= 1) {
            ps += __shfl_xor(ps, o, 16);
            pd += __shfl_xor(pd, o, 16);
        }
        if ((lane & 15) == 0) {
            a_src4[n*4 + (lane >> 4)] = ps;
            a_dst4[n*4 + (lane >> 4)] = pd;
        }
    }
}

// ---- per layer: wave-per-node GAT + bias + residual + LN + ReLU (in-place h) ----
__global__ __launch_bounds__(256) void k_gat(const ushort* __restrict__ xs2, // [N][64] bf16
        const float* __restrict__ a_src4, const float* __restrict__ a_dst4,
        const int* __restrict__ rowptr, const uint4* __restrict__ recs,
        const float4* __restrict__ ea_mean,
        const float* __restrict__ Mc,   // M + l*16
        const float* __restrict__ c0,   // c0 + l*4
        const float* __restrict__ bias, const float* __restrict__ lng,
        const float* __restrict__ lnb, float* __restrict__ hio, int n_nodes)
{
    int n = blockIdx.x*4 + (threadIdx.x >> 6);
    if (n >= n_nodes) return;
    int lane = threadIdx.x & 63;
    int hA  = lane & 3;        // head in logit phase (lane = e*4 + h)
    int k8  = lane & 7;        // channel-octet index in gather phase
    int hB  = k8 >> 1;         // head owning channels 8*k8..8*k8+7
    int grp = lane >> 3;       // edge subgroup 0..7 in gather phase
    int lsel = lane >> 2;      // edge-in-chunk for logit phase
    // early independent loads: residual row + ea_mean
    int cb = k8 * 8;
    const float4* hr = (const float4*)(hio + (size_t)n*64 + cb);
    float4 r0 = hr[0], r1 = hr[1];
    float4 eam = ea_mean[n];
    // phase-A per-head constants
    float m0A = Mc[hA], m1A = Mc[4+hA], m2A = Mc[8+hA], m3A = Mc[12+hA];
    float chA = c0[hA];
    float adA = a_dst4[n*4 + hA];
    int rb = rowptr[n], re = rowptr[n + 1];

    float den = 0.f;
    float a0=0.f,a1=0.f,a2=0.f,a3=0.f,a4=0.f,a5=0.f,a6=0.f,a7=0.f;

    if (rb < re) {
        int sc0 = rb + lsel; if (sc0 >= re) sc0 = re - 1;
        uint4 rec = recs[sc0];
        for (int b = rb; b < re; b += 16) {
            // ---- phase A: logits for 16 edges x 4 heads across 64 lanes ----
            bool valid = (b + lsel) < re;
            int sn = (int)rec.x;
            float al = fmaf(bf_lo(rec.y), m0A, fmaf(bf_hi(rec.y), m1A,
                        fmaf(bf_lo(rec.z), m2A, fmaf(bf_hi(rec.z), m3A, chA))))
                     + a_src4[sn*4 + hA] + adA;
            al = (al > 0.f) ? al : LRELU_SLOPE * al;
            float ev = valid ? __expf(al) : 0.f;
            float ds = ev;
            ds += __shfl_xor(ds, 4);  ds += __shfl_xor(ds, 8);
            ds += __shfl_xor(ds, 16); ds += __shfl_xor(ds, 32);
            den += ds;                                   // replicated per head hA
            // prefetch next chunk's records (overlaps with gather phase)
            uint4 rec_next = rec;
            int nb2 = b + 16;
            if (nb2 < re) {
                int sc = nb2 + lsel; if (sc >= re) sc = re - 1;
                rec_next = recs[sc];
            }
            // ---- phase B: gather+accumulate, 8 edges per iteration ----
            #pragma unroll
            for (int half = 0; half < 2; ++half) {
                if (b + half*8 >= re) break;             // wave-uniform
                int e_loc = half*8 + grp;
                int snb = __shfl(sn, e_loc << 2);
                float w  = __shfl(ev, (e_loc << 2) + hB);
                unsigned int idx = ((unsigned int)snb << 3) + (unsigned int)k8;
                uint4 v = ((const uint4*)xs2)[idx];
                a0 = fmaf(bf_lo(v.x), w, a0); a1 = fmaf(bf_hi(v.x), w, a1);
                a2 = fmaf(bf_lo(v.y), w, a2); a3 = fmaf(bf_hi(v.y), w, a3);
                a4 = fmaf(bf_lo(v.z), w, a4); a5 = fmaf(bf_hi(v.z), w, a5);
                a6 = fmaf(bf_lo(v.w), w, a6); a7 = fmaf(bf_hi(v.w), w, a7);
            }
            rec = rec_next;
        }
    }
    // cross-group reduction (groups 0..7 each hold partial sums)
    #define XR(A) A += __shfl_xor(A, 8); A += __shfl_xor(A, 16); A += __shfl_xor(A, 32);
    XR(a0) XR(a1) XR(a2) XR(a3) XR(a4) XR(a5) XR(a6) XR(a7)
    #undef XR
    // self-loop (edge feature = per-dst mean; zero if deg==0), head hB per lane
    float ael = (re > rb)
        ? fmaf(eam.x, Mc[hB], fmaf(eam.y, Mc[4+hB],
          fmaf(eam.z, Mc[8+hB], fmaf(eam.w, Mc[12+hB], c0[hB]))))
        : 0.f;
    float alS = a_src4[n*4 + hB] + a_dst4[n*4 + hB] + ael;
    alS = (alS > 0.f) ? alS : LRELU_SLOPE * alS;
    float evS = __expf(alS);
    float denF = __shfl(den, hB) + evS;
    unsigned int idxS = ((unsigned int)n << 3) + (unsigned int)k8;
    uint4 vs = ((const uint4*)xs2)[idxS];
    a0 = fmaf(bf_lo(vs.x), evS, a0); a1 = fmaf(bf_hi(vs.x), evS, a1);
    a2 = fmaf(bf_lo(vs.y), evS, a2); a3 = fmaf(bf_hi(vs.y), evS, a3);
    a4 = fmaf(bf_lo(vs.z), evS, a4); a5 = fmaf(bf_hi(vs.z), evS, a5);
    a6 = fmaf(bf_lo(vs.w), evS, a6); a7 = fmaf(bf_hi(vs.w), evS, a7);
    // epilogue: /den + bias + residual, LayerNorm over 64 ch, ReLU
    float inv = 1.f / (denF + 1e-16f);
    const float4* bp = (const float4*)(bias + cb);
    float4 b0 = bp[0], b1 = bp[1];
    float o0 = a0*inv + b0.x + r0.x, o1 = a1*inv + b0.y + r0.y;
    float o2 = a2*inv + b0.z + r0.z, o3 = a3*inv + b0.w + r0.w;
    float o4 = a4*inv + b1.x + r1.x, o5 = a5*inv + b1.y + r1.y;
    float o6 = a6*inv + b1.z + r1.z, o7 = a7*inv + b1.w + r1.w;
    float s1 = o0+o1+o2+o3+o4+o5+o6+o7;
    s1 += __shfl_xor(s1, 1); s1 += __shfl_xor(s1, 2); s1 += __shfl_xor(s1, 4);
    float mu = s1 * 0.015625f;
    float d0=o0-mu,d1=o1-mu,d2=o2-mu,d3=o3-mu,d4=o4-mu,d5=o5-mu,d6=o6-mu,d7=o7-mu;
    float s2 = d0*d0+d1*d1+d2*d2+d3*d3+d4*d4+d5*d5+d6*d6+d7*d7;
    s2 += __shfl_xor(s2, 1); s2 += __shfl_xor(s2, 2); s2 += __shfl_xor(s2, 4);
    float rs = rsqrtf(s2 * 0.015625f + 1e-5f);
    const float4* gp = (const float4*)(lng + cb);
    const float4* zp = (const float4*)(lnb + cb);
    float4 g0 = gp[0], g1 = gp[1], z0 = zp[0], z1 = zp[1];
    float y0 = fmaxf(d0*rs*g0.x + z0.x, 0.f), y1 = fmaxf(d1*rs*g0.y + z0.y, 0.f);
    float y2 = fmaxf(d2*rs*g0.z + z0.z, 0.f), y3 = fmaxf(d3*rs*g0.w + z0.w, 0.f);
    float y4 = fmaxf(d4*rs*g1.x + z1.x, 0.f), y5 = fmaxf(d5*rs*g1.y + z1.y, 0.f);
    float y6 = fmaxf(d6*rs*g1.z + z1.z, 0.f), y7 = fmaxf(d7*rs*g1.w + z1.w, 0.f);
    if (lane < 8) {
        float4* outp = (float4*)(hio + (size_t)n*64 + cb);
        outp[0] = make_float4(y0, y1, y2, y3);
        outp[1] = make_float4(y4, y5, y6, y7);
    }
}

extern "C" void kernel_launch(void* const* d_in, const int* in_sizes, int n_in,
                              void* d_out, int out_size, void* d_ws, size_t ws_size,
                              hipStream_t stream) {
    const float* x          = (const float*)d_in[0];
    const int*   ei         = (const int*)d_in[1];
    const float* edge_attr  = (const float*)d_in[2];
    const float* node_w     = (const float*)d_in[3];
    const float* node_b     = (const float*)d_in[4];
    const float* edge_w     = (const float*)d_in[5];
    const float* edge_b     = (const float*)d_in[6];
    const float* lin_w      = (const float*)d_in[7];
    const float* lin_edge_w = (const float*)d_in[8];
    const float* att_src    = (const float*)d_in[9];
    const float* att_dst    = (const float*)d_in[10];
    const float* att_edge   = (const float*)d_in[11];
    const float* gat_bias   = (const float*)d_in[12];
    const float* ln_g       = (const float*)d_in[13];
    const float* ln_b       = (const float*)d_in[14];

    int NN = in_sizes[0] / 8;
    int E  = in_sizes[1] / 2;
    const int* src = ei;
    const int* dst = ei + E;
    float* h = (float*)d_out;

    char* wsp = (char*)d_ws;
    size_t off = 0;
    auto alloc = [&](size_t bytes) -> void* {
        off = (off + 255) & ~(size_t)255;
        void* p = wsp + off;
        off += bytes;
        return p;
    };
    ushort* xs2     = (ushort*)alloc((size_t)NN * 64 * 2);
    float*  a_src4  = (float*)alloc((size_t)NN * 4 * 4);
    float*  a_dst4  = (float*)alloc((size_t)NN * 4 * 4);
    uint4*  recs    = (uint4*)alloc((size_t)E * 16);
    float4* ea_mean = (float4*)alloc((size_t)NN * 16);
    int*    rowptr  = (int*)alloc((size_t)(NN + 1) * 4);
    int*    degc    = (int*)alloc((size_t)NN * 4);
    int*    rank    = (int*)alloc((size_t)E * 4);
    int*    bsum    = (int*)alloc(512);
    float*  Mc      = (float*)alloc(256);

    hipMemsetAsync(degc, 0, (size_t)NN * 4, stream);
    k_smallw<<<1, 256, 0, stream>>>(lin_edge_w, att_edge, edge_w, edge_b, Mc);
    k_node_proj<<<(NN*64 + 255) / 256, 256, 0, stream>>>(x, node_w, node_b, h, NN);
    k_deg<<<2048, 256, 0, stream>>>(dst, degc, rank, E);
    int nb = (NN + 1023) / 1024;
    k_scan1<<<nb, 1024, 0, stream>>>(degc, rowptr + 1, bsum, NN);
    k_scan2<<<1, 128, 0, stream>>>(bsum, nb);
    k_scan3<<<nb, 1024, 0, stream>>>(rowptr, bsum, NN);
    k_scatter<<<2048, 256, 0, stream>>>(src, dst, rank, (const float4*)edge_attr,
                                        rowptr, recs, E);
    k_eamean<<<(NN + 255) / 256, 256, 0, stream>>>(rowptr, recs, ea_mean, NN);

    for (int l = 0; l < 3; ++l) {
        k_proj<<<2048, 256, 0, stream>>>(h, lin_w + l*4096, att_src + l*64, att_dst + l*64,
                                         xs2, a_src4, a_dst4, NN);
        k_gat<<<(NN + 3) / 4, 256, 0, stream>>>(xs2, a_src4, a_dst4, rowptr, recs,
                                                ea_mean, Mc + l*16, Mc + 48 + l*4,
                                                gat_bias + l*64, ln_g + l*64, ln_b + l*64,
                                                h, NN);
    }
}

// Round 4
// 518.984 us; speedup vs baseline: 1.9483x; 1.1539x over previous
//
#include <hip/hip_runtime.h>

// GAT encoder, MI355X. Algebraic fold: edge features only enter via the logit
// a_edge = edge_attr(4) @ M[l](4x4) + c0[l](4)  (edge proj folded through att_edge).
// CSR-by-dst built with rank-from-histogram (no atomics in scatter), edges stored
// as ONE fused 16B record {src, ea.xy bf16, ea.zw bf16, -}. Wave-per-node GAT,
// depth-2 software pipeline: records/a_src/xs-row gathers for chunk k+1 issued
// during chunk k's FMA phase (hides ~500-900cy gather latency). Branch-free
// inner loop (clamped addresses + zero weights). Messages bf16, logits fp32.
// Fused softmax (shift-invariant) + bias + residual + LayerNorm + ReLU.

#define LRELU_SLOPE 0.2f

__device__ __forceinline__ ushort f2bf(float x) {
    unsigned int b = __float_as_uint(x);
    return (ushort)((b + 0x7fffu + ((b >> 16) & 1u)) >> 16);   // RNE
}
__device__ __forceinline__ unsigned int pack2bf(float a, float b) {
    return (unsigned int)f2bf(a) | ((unsigned int)f2bf(b) << 16);
}
__device__ __forceinline__ float bf_lo(unsigned int v) { return __uint_as_float(v << 16); }
__device__ __forceinline__ float bf_hi(unsigned int v) { return __uint_as_float(v & 0xffff0000u); }

// ---- tiny per-layer weight folding: M[3][4][4], c0[3][4] ----
__global__ void k_smallw(const float* __restrict__ lin_edge_w, // [3][64][64]
                         const float* __restrict__ att_edge,   // [3][4][16]
                         const float* __restrict__ edge_w,     // [4][64]
                         const float* __restrict__ edge_b,     // [64]
                         float* __restrict__ Mc)               // [48] M + [12] c0
{
    __shared__ float we[3][64][4];
    int t = threadIdx.x;
    if (t < 192) {
        int l = t >> 6, k = t & 63;
        for (int h = 0; h < 4; ++h) {
            float acc = 0.f;
            #pragma unroll
            for (int c = 0; c < 16; ++c)
                acc = fmaf(lin_edge_w[l*4096 + k*64 + h*16 + c],
                           att_edge[l*64 + h*16 + c], acc);
            we[l][k][h] = acc;
        }
    }
    __syncthreads();
    if (t < 48) {
        int l = t >> 4, k4 = (t >> 2) & 3, h = t & 3;
        float acc = 0.f;
        for (int k = 0; k < 64; ++k)
            acc = fmaf(edge_w[k4*64 + k], we[l][k][h], acc);
        Mc[l*16 + k4*4 + h] = acc;
    }
    if (t >= 64 && t < 76) {
        int u = t - 64, l = u >> 2, h = u & 3;
        float acc = 0.f;
        for (int k = 0; k < 64; ++k)
            acc = fmaf(edge_b[k], we[l][k][h], acc);
        Mc[48 + l*4 + h] = acc;
    }
}

// ---- h0 = x @ node_w + node_b ----
__global__ void k_node_proj(const float* __restrict__ x, const float* __restrict__ nw,
                            const float* __restrict__ nb, float* __restrict__ h, int n_nodes)
{
    int idx = blockIdx.x * blockDim.x + threadIdx.x;
    int n = idx >> 6, j = idx & 63;
    if (n >= n_nodes) return;
    float acc = nb[j];
    #pragma unroll
    for (int k = 0; k < 8; ++k) acc = fmaf(x[n*8 + k], nw[k*64 + j], acc);
    h[(size_t)n*64 + j] = acc;
}

// ---- CSR build: histogram + per-edge rank (rank = old count) ----
__global__ void k_deg(const int* __restrict__ dst, int* __restrict__ deg,
                      int* __restrict__ rank, int E) {
    for (int e = blockIdx.x*blockDim.x + threadIdx.x; e < E; e += gridDim.x*blockDim.x)
        rank[e] = atomicAdd(&deg[dst[e]], 1);
}

__global__ void k_scan1(const int* __restrict__ deg, int* __restrict__ rowptr1,
                        int* __restrict__ bsum, int n) {
    __shared__ int s[1024];
    int i = blockIdx.x*1024 + threadIdx.x;
    s[threadIdx.x] = (i < n) ? deg[i] : 0;
    __syncthreads();
    for (int off = 1; off < 1024; off <<= 1) {
        int t = (threadIdx.x >= off) ? s[threadIdx.x - off] : 0;
        __syncthreads();
        s[threadIdx.x] += t;
        __syncthreads();
    }
    if (i < n) rowptr1[i] = s[threadIdx.x];           // inclusive chunk scan
    if (threadIdx.x == 1023) bsum[blockIdx.x] = s[1023];
}

__global__ void k_scan2(int* bsum, int nb) {          // nb <= 128, 1 block
    __shared__ int s[128];
    int t = threadIdx.x;
    s[t] = (t < nb) ? bsum[t] : 0;
    __syncthreads();
    for (int off = 1; off < 128; off <<= 1) {
        int v = (t >= off) ? s[t - off] : 0;
        __syncthreads();
        s[t] += v;
        __syncthreads();
    }
    if (t < nb) bsum[t] = (t == 0) ? 0 : s[t - 1];    // exclusive block offsets
}

__global__ void k_scan3(int* __restrict__ rowptr, const int* __restrict__ bsum, int n) {
    int i = blockIdx.x*1024 + threadIdx.x;
    if (i < n) rowptr[i + 1] += bsum[blockIdx.x];
    if (i == 0) rowptr[0] = 0;
}

// one fused 16B record per edge, single random store, no atomics
__global__ void k_scatter(const int* __restrict__ src, const int* __restrict__ dst,
                          const int* __restrict__ rank, const float4* __restrict__ edge_attr,
                          const int* __restrict__ rowptr, uint4* __restrict__ recs, int E) {
    for (int e = blockIdx.x*blockDim.x + threadIdx.x; e < E; e += gridDim.x*blockDim.x) {
        int d = dst[e];
        int slot = rowptr[d] + rank[e];
        float4 ea = edge_attr[e];
        uint4 r;
        r.x = (unsigned int)src[e];
        r.y = pack2bf(ea.x, ea.y);
        r.z = pack2bf(ea.z, ea.w);
        r.w = 0u;
        recs[slot] = r;
    }
}

__global__ void k_eamean(const int* __restrict__ rowptr, const uint4* __restrict__ recs,
                         float4* __restrict__ ea_mean, int n) {
    int i = blockIdx.x*blockDim.x + threadIdx.x;
    if (i >= n) return;
    int b = rowptr[i], e = rowptr[i + 1];
    float sx = 0.f, sy = 0.f, sz = 0.f, sw = 0.f;
    for (int s = b; s < e; ++s) {
        uint4 r = recs[s];
        sx += bf_lo(r.y); sy += bf_hi(r.y); sz += bf_lo(r.z); sw += bf_hi(r.z);
    }
    float inv = (e > b) ? 1.f / (float)(e - b) : 0.f;  // deg=0 -> e_mean = 0
    ea_mean[i] = make_float4(sx*inv, sy*inv, sz*inv, sw*inv);
}

// ---- per layer: xs = h @ lin_w[l] (bf16 out); 4 nodes/wave share W ds_reads ----
__global__ __launch_bounds__(256) void k_proj(const float* __restrict__ h,
        const float* __restrict__ lw,   // lin_w + l*4096
        const float* __restrict__ asw,  // att_src + l*64
        const float* __restrict__ adw,  // att_dst + l*64
        ushort* __restrict__ xs2, float* __restrict__ a_src4, float* __restrict__ a_dst4,
        int n_nodes)
{
    __shared__ float W[4096];
    for (int i = threadIdx.x; i < 4096; i += 256) W[i] = lw[i];
    __syncthreads();
    int lane = threadIdx.x & 63, wid = threadIdx.x >> 6;
    float as_w = asw[lane], ad_w = adw[lane];
    int nquads = (n_nodes + 3) >> 2;
    for (int q = blockIdx.x*4 + wid; q < nquads; q += gridDim.x*4) {
        int n0 = q << 2;
        if (n0 + 3 < n_nodes) {
            float acc0 = 0.f, acc1 = 0.f, acc2 = 0.f, acc3 = 0.f;
            const float4* r0p = (const float4*)(h + (size_t)(n0+0)*64);
            const float4* r1p = (const float4*)(h + (size_t)(n0+1)*64);
            const float4* r2p = (const float4*)(h + (size_t)(n0+2)*64);
            const float4* r3p = (const float4*)(h + (size_t)(n0+3)*64);
            #pragma unroll
            for (int kc = 0; kc < 8; ++kc) {          // 8 k per chunk
                float4 u0 = r0p[kc*2], v0 = r0p[kc*2+1];
                float4 u1 = r1p[kc*2], v1 = r1p[kc*2+1];
                float4 u2 = r2p[kc*2], v2 = r2p[kc*2+1];
                float4 u3 = r3p[kc*2], v3 = r3p[kc*2+1];
                int kb = kc * 8;
                float w0 = W[(kb+0)*64+lane], w1 = W[(kb+1)*64+lane];
                float w2 = W[(kb+2)*64+lane], w3 = W[(kb+3)*64+lane];
                float w4 = W[(kb+4)*64+lane], w5 = W[(kb+5)*64+lane];
                float w6 = W[(kb+6)*64+lane], w7 = W[(kb+7)*64+lane];
                acc0 = fmaf(u0.x,w0, fmaf(u0.y,w1, fmaf(u0.z,w2, fmaf(u0.w,w3,
                       fmaf(v0.x,w4, fmaf(v0.y,w5, fmaf(v0.z,w6, fmaf(v0.w,w7, acc0))))))));
                acc1 = fmaf(u1.x,w0, fmaf(u1.y,w1, fmaf(u1.z,w2, fmaf(u1.w,w3,
                       fmaf(v1.x,w4, fmaf(v1.y,w5, fmaf(v1.z,w6, fmaf(v1.w,w7, acc1))))))));
                acc2 = fmaf(u2.x,w0, fmaf(u2.y,w1, fmaf(u2.z,w2, fmaf(u2.w,w3,
                       fmaf(v2.x,w4, fmaf(v2.y,w5, fmaf(v2.z,w6, fmaf(v2.w,w7, acc2))))))));
                acc3 = fmaf(u3.x,w0, fmaf(u3.y,w1, fmaf(u3.z,w2, fmaf(u3.w,w3,
                       fmaf(v3.x,w4, fmaf(v3.y,w5, fmaf(v3.z,w6, fmaf(v3.w,w7, acc3))))))));
            }
            xs2[(size_t)(n0+0)*64 + lane] = f2bf(acc0);
            xs2[(size_t)(n0+1)*64 + lane] = f2bf(acc1);
            xs2[(size_t)(n0+2)*64 + lane] = f2bf(acc2);
            xs2[(size_t)(n0+3)*64 + lane] = f2bf(acc3);
            #define ARED(ACC, J) { \
                float ps = (ACC)*as_w, pd = (ACC)*ad_w; \
                ps += __shfl_xor(ps,1,16); pd += __shfl_xor(pd,1,16); \
                ps += __shfl_xor(ps,2,16); pd += __shfl_xor(pd,2,16); \
                ps += __shfl_xor(ps,4,16); pd += __shfl_xor(pd,4,16); \
                ps += __shfl_xor(ps,8,16); pd += __shfl_xor(pd,8,16); \
                if ((lane & 15) == 0) { \
                    a_src4[(n0+(J))*4 + (lane>>4)] = ps; \
                    a_dst4[(n0+(J))*4 + (lane>>4)] = pd; \
                } }
            ARED(acc0, 0) ARED(acc1, 1) ARED(acc2, 2) ARED(acc3, 3)
            #undef ARED
        } else {
            for (int n = n0; n < n_nodes; ++n) {
                const float4* rp = (const float4*)(h + (size_t)n*64);
                float acc = 0.f;
                #pragma unroll
                for (int kc = 0; kc < 8; ++kc) {
                    float4 u = rp[kc*2], v = rp[kc*2+1];
                    int kb = kc * 8;
                    acc = fmaf(u.x, W[(kb+0)*64+lane], acc);
                    acc = fmaf(u.y, W[(kb+1)*64+lane], acc);
                    acc = fmaf(u.z, W[(kb+2)*64+lane], acc);
                    acc = fmaf(u.w, W[(kb+3)*64+lane], acc);
                    acc = fmaf(v.x, W[(kb+4)*64+lane], acc);
                    acc = fmaf(v.y, W[(kb+5)*64+lane], acc);
                    acc = fmaf(v.z, W[(kb+6)*64+lane], acc);
                    acc = fmaf(v.w, W[(kb+7)*64+lane], acc);
                }
                xs2[(size_t)n*64 + lane] = f2bf(acc);
                float ps = acc*as_w, pd = acc*ad_w;
                #pragma unroll
                for (int o = 1; o < 16; o <<= 1) {
                    ps += __shfl_xor(ps, o, 16);
                    pd += __shfl_xor(pd, o, 16);
                }
                if ((lane & 15) == 0) {
                    a_src4[n*4 + (lane>>4)] = ps;
                    a_dst4[n*4 + (lane>>4)] = pd;
                }
            }
        }
    }
}

// ---- per layer: wave-per-node GAT, depth-2 pipelined, + bias+res+LN+ReLU ----
__global__ __launch_bounds__(256) void k_gat(const ushort* __restrict__ xs2, // [N][64] bf16
        const float* __restrict__ a_src4, const float* __restrict__ a_dst4,
        const int* __restrict__ rowptr, const uint4* __restrict__ recs,
        const float4* __restrict__ ea_mean,
        const float* __restrict__ Mc,   // M + l*16
        const float* __restrict__ c0,   // c0 + l*4
        const float* __restrict__ bias, const float* __restrict__ lng,
        const float* __restrict__ lnb, float* __restrict__ hio, int n_nodes)
{
    int n = blockIdx.x*4 + (threadIdx.x >> 6);
    if (n >= n_nodes) return;
    int lane = threadIdx.x & 63;
    int hA  = lane & 3;        // head in logit phase (lane = e*4 + h)
    int k8  = lane & 7;        // channel-octet index in gather phase
    int hB  = k8 >> 1;         // head owning channels 8*k8..8*k8+7
    int grp = lane >> 3;       // edge subgroup 0..7 in gather phase
    int lsel = lane >> 2;      // edge-in-chunk for logit phase
    // early independent loads: residual row + ea_mean
    int cb = k8 * 8;
    const float4* hr = (const float4*)(hio + (size_t)n*64 + cb);
    float4 r0 = hr[0], r1 = hr[1];
    float4 eam = ea_mean[n];
    float m0A = Mc[hA], m1A = Mc[4+hA], m2A = Mc[8+hA], m3A = Mc[12+hA];
    float chA = c0[hA];
    float adA = a_dst4[n*4 + hA];
    int rb = rowptr[n], re = rowptr[n + 1];
    const uint4* xs4 = (const uint4*)xs2;

    float denL = 0.f;
    float a0=0.f,a1=0.f,a2=0.f,a3=0.f,a4=0.f,a5=0.f,a6=0.f,a7=0.f;

    if (rb < re) {
        int last = re - 1;
        // ---- prologue: chunk 0 fully issued; chunk 1 record issued ----
        int i0 = rb + lsel;      i0 = (i0 > last) ? last : i0;
        uint4 rec  = recs[i0];
        int i1 = rb + 16 + lsel; i1 = (i1 > last) ? last : i1;
        uint4 rec1 = recs[i1];
        int sn = (int)rec.x;
        float asv = a_src4[sn*4 + hA];
        int sa = __shfl(sn, grp << 2);
        int sb = __shfl(sn, (grp + 8) << 2);
        uint4 va = xs4[((unsigned)sa << 3) + k8];
        uint4 vb = xs4[((unsigned)sb << 3) + k8];
        for (int b = rb; b < re; b += 16) {
            // issue chunk b+32 record
            int i2 = b + 32 + lsel; i2 = (i2 > last) ? last : i2;
            uint4 rec2 = recs[i2];
            // issue chunk b+16: a_src gather + xs-row gathers
            int sn1 = (int)rec1.x;
            float asv1 = a_src4[sn1*4 + hA];
            int sa1 = __shfl(sn1, grp << 2);
            int sb1 = __shfl(sn1, (grp + 8) << 2);
            uint4 va1 = xs4[((unsigned)sa1 << 3) + k8];
            uint4 vb1 = xs4[((unsigned)sb1 << 3) + k8];
            // logits for chunk b (rec, asv already resident)
            float al = fmaf(bf_lo(rec.y), m0A, fmaf(bf_hi(rec.y), m1A,
                       fmaf(bf_lo(rec.z), m2A, fmaf(bf_hi(rec.z), m3A, chA))))
                     + asv + adA;
            al = (al > 0.f) ? al : LRELU_SLOPE * al;
            float ev = (b + lsel < re) ? __expf(al) : 0.f;
            denL += ev;
            float wa = __shfl(ev, (grp << 2) + hB);
            float wb = __shfl(ev, ((grp + 8) << 2) + hB);
            // FMA chunk b (va/vb issued one iteration ago)
            a0 = fmaf(bf_lo(va.x), wa, a0); a1 = fmaf(bf_hi(va.x), wa, a1);
            a2 = fmaf(bf_lo(va.y), wa, a2); a3 = fmaf(bf_hi(va.y), wa, a3);
            a4 = fmaf(bf_lo(va.z), wa, a4); a5 = fmaf(bf_hi(va.z), wa, a5);
            a6 = fmaf(bf_lo(va.w), wa, a6); a7 = fmaf(bf_hi(va.w), wa, a7);
            a0 = fmaf(bf_lo(vb.x), wb, a0); a1 = fmaf(bf_hi(vb.x), wb, a1);
            a2 = fmaf(bf_lo(vb.y), wb, a2); a3 = fmaf(bf_hi(vb.y), wb, a3);
            a4 = fmaf(bf_lo(vb.z), wb, a4); a5 = fmaf(bf_hi(vb.z), wb, a5);
            a6 = fmaf(bf_lo(vb.w), wb, a6); a7 = fmaf(bf_hi(vb.w), wb, a7);
            // rotate pipeline registers
            rec = rec1; rec1 = rec2; asv = asv1; va = va1; vb = vb1;
        }
        // one-time den reduction (preserves lane&3 = head partition)
        denL += __shfl_xor(denL, 4);  denL += __shfl_xor(denL, 8);
        denL += __shfl_xor(denL, 16); denL += __shfl_xor(denL, 32);
    }
    // cross-group reduction (groups 0..7 each hold partial channel sums)
    #define XR(A) A += __shfl_xor(A, 8); A += __shfl_xor(A, 16); A += __shfl_xor(A, 32);
    XR(a0) XR(a1) XR(a2) XR(a3) XR(a4) XR(a5) XR(a6) XR(a7)
    #undef XR
    // self-loop (edge feature = per-dst mean; zero if deg==0), head hB per lane
    float ael = (re > rb)
        ? fmaf(eam.x, Mc[hB], fmaf(eam.y, Mc[4+hB],
          fmaf(eam.z, Mc[8+hB], fmaf(eam.w, Mc[12+hB], c0[hB]))))
        : 0.f;
    float alS = a_src4[n*4 + hB] + a_dst4[n*4 + hB] + ael;
    alS = (alS > 0.f) ? alS : LRELU_SLOPE * alS;
    float evS = __expf(alS);
    float denF = __shfl(denL, hB) + evS;
    unsigned int idxS = ((unsigned int)n << 3) + (unsigned int)k8;
    uint4 vs = xs4[idxS];
    a0 = fmaf(bf_lo(vs.x), evS, a0); a1 = fmaf(bf_hi(vs.x), evS, a1);
    a2 = fmaf(bf_lo(vs.y), evS, a2); a3 = fmaf(bf_hi(vs.y), evS, a3);
    a4 = fmaf(bf_lo(vs.z), evS, a4); a5 = fmaf(bf_hi(vs.z), evS, a5);
    a6 = fmaf(bf_lo(vs.w), evS, a6); a7 = fmaf(bf_hi(vs.w), evS, a7);
    // epilogue: /den + bias + residual, LayerNorm over 64 ch, ReLU
    float inv = 1.f / (denF + 1e-16f);
    const float4* bp = (const float4*)(bias + cb);
    float4 b0 = bp[0], b1 = bp[1];
    float o0 = a0*inv + b0.x + r0.x, o1 = a1*inv + b0.y + r0.y;
    float o2 = a2*inv + b0.z + r0.z, o3 = a3*inv + b0.w + r0.w;
    float o4 = a4*inv + b1.x + r1.x, o5 = a5*inv + b1.y + r1.y;
    float o6 = a6*inv + b1.z + r1.z, o7 = a7*inv + b1.w + r1.w;
    float s1 = o0+o1+o2+o3+o4+o5+o6+o7;
    s1 += __shfl_xor(s1, 1); s1 += __shfl_xor(s1, 2); s1 += __shfl_xor(s1, 4);
    float mu = s1 * 0.015625f;
    float d0=o0-mu,d1=o1-mu,d2=o2-mu,d3=o3-mu,d4=o4-mu,d5=o5-mu,d6=o6-mu,d7=o7-mu;
    float s2 = d0*d0+d1*d1+d2*d2+d3*d3+d4*d4+d5*d5+d6*d6+d7*d7;
    s2 += __shfl_xor(s2, 1); s2 += __shfl_xor(s2, 2); s2 += __shfl_xor(s2, 4);
    float rs = rsqrtf(s2 * 0.015625f + 1e-5f);
    const float4* gp = (const float4*)(lng + cb);
    const float4* zp = (const float4*)(lnb + cb);
    float4 g0 = gp[0], g1 = gp[1], z0 = zp[0], z1 = zp[1];
    float y0 = fmaxf(d0*rs*g0.x + z0.x, 0.f), y1 = fmaxf(d1*rs*g0.y + z0.y, 0.f);
    float y2 = fmaxf(d2*rs*g0.z + z0.z, 0.f), y3 = fmaxf(d3*rs*g0.w + z0.w, 0.f);
    float y4 = fmaxf(d4*rs*g1.x + z1.x, 0.f), y5 = fmaxf(d5*rs*g1.y + z1.y, 0.f);
    float y6 = fmaxf(d6*rs*g1.z + z1.z, 0.f), y7 = fmaxf(d7*rs*g1.w + z1.w, 0.f);
    if (lane < 8) {
        float4* outp = (float4*)(hio + (size_t)n*64 + cb);
        outp[0] = make_float4(y0, y1, y2, y3);
        outp[1] = make_float4(y4, y5, y6, y7);
    }
}

extern "C" void kernel_launch(void* const* d_in, const int* in_sizes, int n_in,
                              void* d_out, int out_size, void* d_ws, size_t ws_size,
                              hipStream_t stream) {
    const float* x          = (const float*)d_in[0];
    const int*   ei         = (const int*)d_in[1];
    const float* edge_attr  = (const float*)d_in[2];
    const float* node_w     = (const float*)d_in[3];
    const float* node_b     = (const float*)d_in[4];
    const float* edge_w     = (const float*)d_in[5];
    const float* edge_b     = (const float*)d_in[6];
    const float* lin_w      = (const float*)d_in[7];
    const float* lin_edge_w = (const float*)d_in[8];
    const float* att_src    = (const float*)d_in[9];
    const float* att_dst    = (const float*)d_in[10];
    const float* att_edge   = (const float*)d_in[11];
    const float* gat_bias   = (const float*)d_in[12];
    const float* ln_g       = (const float*)d_in[13];
    const float* ln_b       = (const float*)d_in[14];

    int NN = in_sizes[0] / 8;
    int E  = in_sizes[1] / 2;
    const int* src = ei;
    const int* dst = ei + E;
    float* h = (float*)d_out;

    char* wsp = (char*)d_ws;
    size_t off = 0;
    auto alloc = [&](size_t bytes) -> void* {
        off = (off + 255) & ~(size_t)255;
        void* p = wsp + off;
        off += bytes;
        return p;
    };
    ushort* xs2     = (ushort*)alloc((size_t)NN * 64 * 2);
    float*  a_src4  = (float*)alloc((size_t)NN * 4 * 4);
    float*  a_dst4  = (float*)alloc((size_t)NN * 4 * 4);
    uint4*  recs    = (uint4*)alloc((size_t)E * 16);
    float4* ea_mean = (float4*)alloc((size_t)NN * 16);
    int*    rowptr  = (int*)alloc((size_t)(NN + 1) * 4);
    int*    degc    = (int*)alloc((size_t)NN * 4);
    int*    rank    = (int*)alloc((size_t)E * 4);
    int*    bsum    = (int*)alloc(512);
    float*  Mc      = (float*)alloc(256);

    hipMemsetAsync(degc, 0, (size_t)NN * 4, stream);
    k_smallw<<<1, 256, 0, stream>>>(lin_edge_w, att_edge, edge_w, edge_b, Mc);
    k_node_proj<<<(NN*64 + 255) / 256, 256, 0, stream>>>(x, node_w, node_b, h, NN);
    k_deg<<<2048, 256, 0, stream>>>(dst, degc, rank, E);
    int nb = (NN + 1023) / 1024;
    k_scan1<<<nb, 1024, 0, stream>>>(degc, rowptr + 1, bsum, NN);
    k_scan2<<<1, 128, 0, stream>>>(bsum, nb);
    k_scan3<<<nb, 1024, 0, stream>>>(rowptr, bsum, NN);
    k_scatter<<<2048, 256, 0, stream>>>(src, dst, rank, (const float4*)edge_attr,
                                        rowptr, recs, E);
    k_eamean<<<(NN + 255) / 256, 256, 0, stream>>>(rowptr, recs, ea_mean, NN);

    for (int l = 0; l < 3; ++l) {
        k_proj<<<2048, 256, 0, stream>>>(h, lin_w + l*4096, att_src + l*64, att_dst + l*64,
                                         xs2, a_src4, a_dst4, NN);
        k_gat<<<(NN + 3) / 4, 256, 0, stream>>>(xs2, a_src4, a_dst4, rowptr, recs,
                                                ea_mean, Mc + l*16, Mc + 48 + l*4,
                                                gat_bias + l*64, ln_g + l*64, ln_b + l*64,
                                                h, NN);
    }
}

// Round 6
// 498.110 us; speedup vs baseline: 2.0299x; 1.0419x over previous
//
#include <hip/hip_runtime.h>

// GAT encoder, MI355X. Algebraic fold: edge features only enter via the logit
// a_edge = edge_attr(4) @ M[l](4x4) + c0[l](4). CSR-by-dst, edge record = uint2
// {src, edge_attr as 4xfp8-e4m3}  (fp8 is safe for LOGITS only: |a_edge|~0.06,
// 6% rel err -> ~4e-3 logit shift). Messages xs stay BF16 [N][64] (fp8 messages
// failed: 0.18 absmax). Wave-per-node GAT, lane-local layout (lane = edge-grp*8
// + channel-octet k8): each lane computes its own edge's logit (2x head
// redundancy) and gathers its own 16B xs octet -> ZERO cross-lane ops in the
// hot loop; depth-2 software pipeline hides gather latency. Logits in exp2
// domain (log2e folded into Mc/c0/att weights at the producer side).
// Fused softmax (shift-invariant) + bias + residual + LayerNorm + ReLU.

#define LRELU_SLOPE 0.2f
#define LOG2E 1.4426950408889634f

typedef float f32x2 __attribute__((ext_vector_type(2)));

__device__ __forceinline__ f32x2 fp8lo(unsigned int v) {
    return __builtin_amdgcn_cvt_pk_f32_fp8((int)v, false);
}
__device__ __forceinline__ f32x2 fp8hi(unsigned int v) {
    return __builtin_amdgcn_cvt_pk_f32_fp8((int)v, true);
}
__device__ __forceinline__ ushort f2bf(float x) {
    unsigned int b = __float_as_uint(x);
    return (ushort)((b + 0x7fffu + ((b >> 16) & 1u)) >> 16);   // RNE
}
__device__ __forceinline__ float bf_lo(unsigned int v) { return __uint_as_float(v << 16); }
__device__ __forceinline__ float bf_hi(unsigned int v) { return __uint_as_float(v & 0xffff0000u); }

// ---- tiny per-layer weight folding: M[3][4][4], c0[3][4], pre-scaled by log2e ----
__global__ void k_smallw(const float* __restrict__ lin_edge_w, // [3][64][64]
                         const float* __restrict__ att_edge,   // [3][4][16]
                         const float* __restrict__ edge_w,     // [4][64]
                         const float* __restrict__ edge_b,     // [64]
                         float* __restrict__ Mc)               // [48] M + [12] c0
{
    __shared__ float we[3][64][4];
    int t = threadIdx.x;
    if (t < 192) {
        int l = t >> 6, k = t & 63;
        for (int h = 0; h < 4; ++h) {
            float acc = 0.f;
            #pragma unroll
            for (int c = 0; c < 16; ++c)
                acc = fmaf(lin_edge_w[l*4096 + k*64 + h*16 + c],
                           att_edge[l*64 + h*16 + c], acc);
            we[l][k][h] = acc;
        }
    }
    __syncthreads();
    if (t < 48) {
        int l = t >> 4, k4 = (t >> 2) & 3, h = t & 3;
        float acc = 0.f;
        for (int k = 0; k < 64; ++k)
            acc = fmaf(edge_w[k4*64 + k], we[l][k][h], acc);
        Mc[l*16 + k4*4 + h] = acc * LOG2E;
    }
    if (t >= 64 && t < 76) {
        int u = t - 64, l = u >> 2, h = u & 3;
        float acc = 0.f;
        for (int k = 0; k < 64; ++k)
            acc = fmaf(edge_b[k], we[l][k][h], acc);
        Mc[48 + l*4 + h] = acc * LOG2E;
    }
}

// ---- h0 = x @ node_w + node_b ----
__global__ void k_node_proj(const float* __restrict__ x, const float* __restrict__ nw,
                            const float* __restrict__ nb, float* __restrict__ h, int n_nodes)
{
    int idx = blockIdx.x * blockDim.x + threadIdx.x;
    int n = idx >> 6, j = idx & 63;
    if (n >= n_nodes) return;
    float acc = nb[j];
    #pragma unroll
    for (int k = 0; k < 8; ++k) acc = fmaf(x[n*8 + k], nw[k*64 + j], acc);
    h[(size_t)n*64 + j] = acc;
}

// ---- CSR build: histogram + per-edge rank (rank = old count) ----
__global__ void k_deg(const int* __restrict__ dst, int* __restrict__ deg,
                      int* __restrict__ rank, int E) {
    for (int e = blockIdx.x*blockDim.x + threadIdx.x; e < E; e += gridDim.x*blockDim.x)
        rank[e] = atomicAdd(&deg[dst[e]], 1);
}

__global__ void k_scan1(const int* __restrict__ deg, int* __restrict__ rowptr1,
                        int* __restrict__ bsum, int n) {
    __shared__ int s[1024];
    int i = blockIdx.x*1024 + threadIdx.x;
    s[threadIdx.x] = (i < n) ? deg[i] : 0;
    __syncthreads();
    for (int off = 1; off < 1024; off <<= 1) {
        int t = (threadIdx.x >= off) ? s[threadIdx.x - off] : 0;
        __syncthreads();
        s[threadIdx.x] += t;
        __syncthreads();
    }
    if (i < n) rowptr1[i] = s[threadIdx.x];           // inclusive chunk scan
    if (threadIdx.x == 1023) bsum[blockIdx.x] = s[1023];
}

__global__ void k_scan2(int* bsum, int nb) {          // nb <= 128, 1 block
    __shared__ int s[128];
    int t = threadIdx.x;
    s[t] = (t < nb) ? bsum[t] : 0;
    __syncthreads();
    for (int off = 1; off < 128; off <<= 1) {
        int v = (t >= off) ? s[t - off] : 0;
        __syncthreads();
        s[t] += v;
        __syncthreads();
    }
    if (t < nb) bsum[t] = (t == 0) ? 0 : s[t - 1];    // exclusive block offsets
}

__global__ void k_scan3(int* __restrict__ rowptr, const int* __restrict__ bsum, int n) {
    int i = blockIdx.x*1024 + threadIdx.x;
    if (i < n) rowptr[i + 1] += bsum[blockIdx.x];
    if (i == 0) rowptr[0] = 0;
}

// one fused 8B record per edge, single random store, no atomics
__global__ void k_scatter(const int* __restrict__ src, const int* __restrict__ dst,
                          const int* __restrict__ rank, const float4* __restrict__ edge_attr,
                          const int* __restrict__ rowptr, uint2* __restrict__ recs, int E) {
    for (int e = blockIdx.x*blockDim.x + threadIdx.x; e < E; e += gridDim.x*blockDim.x) {
        int d = dst[e];
        int slot = rowptr[d] + rank[e];
        float4 ea = edge_attr[e];
        unsigned int p = (unsigned int)__builtin_amdgcn_cvt_pk_fp8_f32(ea.x, ea.y, 0, false);
        p = (unsigned int)__builtin_amdgcn_cvt_pk_fp8_f32(ea.z, ea.w, (int)p, true);
        uint2 r;
        r.x = (unsigned int)src[e];
        r.y = p;
        recs[slot] = r;
    }
}

__global__ void k_eamean(const int* __restrict__ rowptr, const uint2* __restrict__ recs,
                         float4* __restrict__ ea_mean, int n) {
    int i = blockIdx.x*blockDim.x + threadIdx.x;
    if (i >= n) return;
    int b = rowptr[i], e = rowptr[i + 1];
    float sx = 0.f, sy = 0.f, sz = 0.f, sw = 0.f;
    for (int s = b; s < e; ++s) {
        unsigned int p = recs[s].y;
        f32x2 lo = fp8lo(p), hi = fp8hi(p);
        sx += lo.x; sy += lo.y; sz += hi.x; sw += hi.y;
    }
    float inv = (e > b) ? 1.f / (float)(e - b) : 0.f;  // deg=0 -> e_mean = 0
    ea_mean[i] = make_float4(sx*inv, sy*inv, sz*inv, sw*inv);
}

// ---- per layer: xs = h @ lin_w[l] (bf16 out); 4 nodes/wave share W ds_reads ----
__global__ __launch_bounds__(256) void k_proj(const float* __restrict__ h,
        const float* __restrict__ lw,   // lin_w + l*4096
        const float* __restrict__ asw,  // att_src + l*64
        const float* __restrict__ adw,  // att_dst + l*64
        ushort* __restrict__ xs2, float* __restrict__ a_src4,
        float* __restrict__ a_dst4, int n_nodes)
{
    __shared__ float W[4096];
    for (int i = threadIdx.x; i < 4096; i += 256) W[i] = lw[i];
    __syncthreads();
    int lane = threadIdx.x & 63, wid = threadIdx.x >> 6;
    float as_w = asw[lane] * LOG2E, ad_w = adw[lane] * LOG2E;  // exp2-domain logits
    int nquads = (n_nodes + 3) >> 2;
    for (int q = blockIdx.x*4 + wid; q < nquads; q += gridDim.x*4) {
        int n0 = q << 2;
        if (n0 + 3 < n_nodes) {
            float acc0 = 0.f, acc1 = 0.f, acc2 = 0.f, acc3 = 0.f;
            const float4* r0p = (const float4*)(h + (size_t)(n0+0)*64);
            const float4* r1p = (const float4*)(h + (size_t)(n0+1)*64);
            const float4* r2p = (const float4*)(h + (size_t)(n0+2)*64);
            const float4* r3p = (const float4*)(h + (size_t)(n0+3)*64);
            #pragma unroll
            for (int kc = 0; kc < 8; ++kc) {          // 8 k per chunk
                float4 u0 = r0p[kc*2], v0 = r0p[kc*2+1];
                float4 u1 = r1p[kc*2], v1 = r1p[kc*2+1];
                float4 u2 = r2p[kc*2], v2 = r2p[kc*2+1];
                float4 u3 = r3p[kc*2], v3 = r3p[kc*2+1];
                int kb = kc * 8;
                float w0 = W[(kb+0)*64+lane], w1 = W[(kb+1)*64+lane];
                float w2 = W[(kb+2)*64+lane], w3 = W[(kb+3)*64+lane];
                float w4 = W[(kb+4)*64+lane], w5 = W[(kb+5)*64+lane];
                float w6 = W[(kb+6)*64+lane], w7 = W[(kb+7)*64+lane];
                acc0 = fmaf(u0.x,w0, fmaf(u0.y,w1, fmaf(u0.z,w2, fmaf(u0.w,w3,
                       fmaf(v0.x,w4, fmaf(v0.y,w5, fmaf(v0.z,w6, fmaf(v0.w,w7, acc0))))))));
                acc1 = fmaf(u1.x,w0, fmaf(u1.y,w1, fmaf(u1.z,w2, fmaf(u1.w,w3,
                       fmaf(v1.x,w4, fmaf(v1.y,w5, fmaf(v1.z,w6, fmaf(v1.w,w7, acc1))))))));
                acc2 = fmaf(u2.x,w0, fmaf(u2.y,w1, fmaf(u2.z,w2, fmaf(u2.w,w3,
                       fmaf(v2.x,w4, fmaf(v2.y,w5, fmaf(v2.z,w6, fmaf(v2.w,w7, acc2))))))));
                acc3 = fmaf(u3.x,w0, fmaf(u3.y,w1, fmaf(u3.z,w2, fmaf(u3.w,w3,
                       fmaf(v3.x,w4, fmaf(v3.y,w5, fmaf(v3.z,w6, fmaf(v3.w,w7, acc3))))))));
            }
            xs2[(size_t)(n0+0)*64 + lane] = f2bf(acc0);
            xs2[(size_t)(n0+1)*64 + lane] = f2bf(acc1);
            xs2[(size_t)(n0+2)*64 + lane] = f2bf(acc2);
            xs2[(size_t)(n0+3)*64 + lane] = f2bf(acc3);
            #define ARED(ACC, J) { \
                float ps = (ACC)*as_w, pd = (ACC)*ad_w; \
                ps += __shfl_xor(ps,1,16); pd += __shfl_xor(pd,1,16); \
                ps += __shfl_xor(ps,2,16); pd += __shfl_xor(pd,2,16); \
                ps += __shfl_xor(ps,4,16); pd += __shfl_xor(pd,4,16); \
                ps += __shfl_xor(ps,8,16); pd += __shfl_xor(pd,8,16); \
                if ((lane & 15) == 0) { \
                    a_src4[(n0+(J))*4 + (lane>>4)] = ps; \
                    a_dst4[(n0+(J))*4 + (lane>>4)] = pd; \
                } }
            ARED(acc0, 0) ARED(acc1, 1) ARED(acc2, 2) ARED(acc3, 3)
            #undef ARED
        } else {
            for (int n = n0; n < n_nodes; ++n) {
                const float4* rp = (const float4*)(h + (size_t)n*64);
                float acc = 0.f;
                #pragma unroll
                for (int kc = 0; kc < 8; ++kc) {
                    float4 u = rp[kc*2], v = rp[kc*2+1];
                    int kb = kc * 8;
                    acc = fmaf(u.x, W[(kb+0)*64+lane], acc);
                    acc = fmaf(u.y, W[(kb+1)*64+lane], acc);
                    acc = fmaf(u.z, W[(kb+2)*64+lane], acc);
                    acc = fmaf(u.w, W[(kb+3)*64+lane], acc);
                    acc = fmaf(v.x, W[(kb+4)*64+lane], acc);
                    acc = fmaf(v.y, W[(kb+5)*64+lane], acc);
                    acc = fmaf(v.z, W[(kb+6)*64+lane], acc);
                    acc = fmaf(v.w, W[(kb+7)*64+lane], acc);
                }
                xs2[(size_t)n*64 + lane] = f2bf(acc);
                float ps = acc*as_w, pd = acc*ad_w;
                #pragma unroll
                for (int o = 1; o < 16; o <<= 1) {
                    ps += __shfl_xor(ps, o, 16);
                    pd += __shfl_xor(pd, o, 16);
                }
                if ((lane & 15) == 0) {
                    a_src4[n*4 + (lane>>4)] = ps;
                    a_dst4[n*4 + (lane>>4)] = pd;
                }
            }
        }
    }
}

// ---- per layer: wave-per-node GAT, lane-local, depth-2 pipelined ----
// lane = grp*8 + k8; grp = edge slot (8 edges/chunk), k8 = channel octet,
// head hB = k8>>1. Zero cross-lane ops in the loop. xs gather: lane reads its
// own 16B octet of the 128B bf16 row (8 same-src lanes coalesce to 1 line).
__global__ __launch_bounds__(256) void k_gat(const uint4* __restrict__ xs4, // [N][8] bf16x8
        const float* __restrict__ a_src4, const float* __restrict__ a_dst4,
        const int* __restrict__ rowptr, const uint2* __restrict__ recs,
        const float4* __restrict__ ea_mean,
        const float* __restrict__ Mc,   // M + l*16   (log2e-scaled)
        const float* __restrict__ c0,   // c0 + l*4   (log2e-scaled)
        const float* __restrict__ bias, const float* __restrict__ lng,
        const float* __restrict__ lnb, float* __restrict__ hio, int n_nodes)
{
    int n = blockIdx.x*4 + (threadIdx.x >> 6);
    if (n >= n_nodes) return;
    int lane = threadIdx.x & 63;
    int k8  = lane & 7;        // channel-octet index
    int hB  = k8 >> 1;         // head owning channels 8*k8..8*k8+7
    int grp = lane >> 3;       // edge slot 0..7 within a chunk
    int cb = k8 * 8;
    // early independent loads: residual row + ea_mean
    const float4* hr = (const float4*)(hio + (size_t)n*64 + cb);
    float4 r0 = hr[0], r1 = hr[1];
    float4 eam = ea_mean[n];
    float m0 = Mc[hB], m1 = Mc[4+hB], m2 = Mc[8+hB], m3 = Mc[12+hB];
    float c0v = c0[hB];
    float adv = a_dst4[n*4 + hB];
    float cc = c0v + adv;
    int rb = rowptr[n], re = rowptr[n + 1];

    float denL = 0.f;
    float a0=0.f,a1=0.f,a2=0.f,a3=0.f,a4=0.f,a5=0.f,a6=0.f,a7=0.f;

    if (rb < re) {
        int last = re - 1;
        int i0 = rb + grp;     i0 = (i0 > last) ? last : i0;
        uint2 rc = recs[i0];
        int i1 = rb + 8 + grp; i1 = (i1 > last) ? last : i1;
        uint2 rn = recs[i1];
        float asc = a_src4[(int)rc.x*4 + hB];
        uint4 xc = xs4[(unsigned)rc.x*8u + (unsigned)k8];
        for (int b = rb; b < re; b += 8) {
            // issue chunk b+16 record, chunk b+8 a_src + xs gathers
            int i2 = b + 16 + grp; i2 = (i2 > last) ? last : i2;
            uint2 r2 = recs[i2];
            float asn = a_src4[(int)rn.x*4 + hB];
            uint4 xn = xs4[(unsigned)rn.x*8u + (unsigned)k8];
            // logit for this lane's edge (exp2 domain)
            f32x2 e01 = fp8lo(rc.y), e23 = fp8hi(rc.y);
            float al = fmaf(e01.x, m0, fmaf(e01.y, m1,
                       fmaf(e23.x, m2, fmaf(e23.y, m3, cc)))) + asc;
            al = fmaxf(al, LRELU_SLOPE * al);
            float ev = (b + grp < re) ? exp2f(al) : 0.f;
            denL += ev;
            // 8-channel FMA from resident bf16 octet
            a0 = fmaf(bf_lo(xc.x), ev, a0); a1 = fmaf(bf_hi(xc.x), ev, a1);
            a2 = fmaf(bf_lo(xc.y), ev, a2); a3 = fmaf(bf_hi(xc.y), ev, a3);
            a4 = fmaf(bf_lo(xc.z), ev, a4); a5 = fmaf(bf_hi(xc.z), ev, a5);
            a6 = fmaf(bf_lo(xc.w), ev, a6); a7 = fmaf(bf_hi(xc.w), ev, a7);
            // rotate pipeline registers
            rc = rn; rn = r2; asc = asn; xc = xn;
        }
    }
    // reduce den + channel accumulators across the 8 edge slots
    denL += __shfl_xor(denL, 8); denL += __shfl_xor(denL, 16); denL += __shfl_xor(denL, 32);
    #define XR(A) A += __shfl_xor(A, 8); A += __shfl_xor(A, 16); A += __shfl_xor(A, 32);
    XR(a0) XR(a1) XR(a2) XR(a3) XR(a4) XR(a5) XR(a6) XR(a7)
    #undef XR
    // self-loop (edge feature = per-dst mean; exactly 0 if deg==0)
    float ael = (re > rb)
        ? fmaf(eam.x, m0, fmaf(eam.y, m1, fmaf(eam.z, m2, fmaf(eam.w, m3, c0v))))
        : 0.f;
    float alS = a_src4[n*4 + hB] + adv + ael;
    alS = fmaxf(alS, LRELU_SLOPE * alS);
    float evS = exp2f(alS);
    float denF = denL + evS;
    uint4 vs = xs4[(unsigned)n*8u + (unsigned)k8];
    a0 = fmaf(bf_lo(vs.x), evS, a0); a1 = fmaf(bf_hi(vs.x), evS, a1);
    a2 = fmaf(bf_lo(vs.y), evS, a2); a3 = fmaf(bf_hi(vs.y), evS, a3);
    a4 = fmaf(bf_lo(vs.z), evS, a4); a5 = fmaf(bf_hi(vs.z), evS, a5);
    a6 = fmaf(bf_lo(vs.w), evS, a6); a7 = fmaf(bf_hi(vs.w), evS, a7);
    // epilogue: /den + bias + residual, LayerNorm over 64 ch, ReLU
    float inv = 1.f / (denF + 1e-16f);
    const float4* bp = (const float4*)(bias + cb);
    float4 b0 = bp[0], b1 = bp[1];
    float o0 = a0*inv + b0.x + r0.x, o1 = a1*inv + b0.y + r0.y;
    float o2 = a2*inv + b0.z + r0.z, o3 = a3*inv + b0.w + r0.w;
    float o4 = a4*inv + b1.x + r1.x, o5 = a5*inv + b1.y + r1.y;
    float o6 = a6*inv + b1.z + r1.z, o7 = a7*inv + b1.w + r1.w;
    float s1 = o0+o1+o2+o3+o4+o5+o6+o7;
    s1 += __shfl_xor(s1, 1); s1 += __shfl_xor(s1, 2); s1 += __shfl_xor(s1, 4);
    float mu = s1 * 0.015625f;
    float d0=o0-mu,d1=o1-mu,d2=o2-mu,d3=o3-mu,d4=o4-mu,d5=o5-mu,d6=o6-mu,d7=o7-mu;
    float s2 = d0*d0+d1*d1+d2*d2+d3*d3+d4*d4+d5*d5+d6*d6+d7*d7;
    s2 += __shfl_xor(s2, 1); s2 += __shfl_xor(s2, 2); s2 += __shfl_xor(s2, 4);
    float rs = rsqrtf(s2 * 0.015625f + 1e-5f);
    const float4* gp = (const float4*)(lng + cb);
    const float4* zp = (const float4*)(lnb + cb);
    float4 g0 = gp[0], g1 = gp[1], z0 = zp[0], z1 = zp[1];
    float y0 = fmaxf(d0*rs*g0.x + z0.x, 0.f), y1 = fmaxf(d1*rs*g0.y + z0.y, 0.f);
    float y2 = fmaxf(d2*rs*g0.z + z0.z, 0.f), y3 = fmaxf(d3*rs*g0.w + z0.w, 0.f);
    float y4 = fmaxf(d4*rs*g1.x + z1.x, 0.f), y5 = fmaxf(d5*rs*g1.y + z1.y, 0.f);
    float y6 = fmaxf(d6*rs*g1.z + z1.z, 0.f), y7 = fmaxf(d7*rs*g1.w + z1.w, 0.f);
    if (lane < 8) {
        float4* outp = (float4*)(hio + (size_t)n*64 + cb);
        outp[0] = make_float4(y0, y1, y2, y3);
        outp[1] = make_float4(y4, y5, y6, y7);
    }
}

extern "C" void kernel_launch(void* const* d_in, const int* in_sizes, int n_in,
                              void* d_out, int out_size, void* d_ws, size_t ws_size,
                              hipStream_t stream) {
    const float* x          = (const float*)d_in[0];
    const int*   ei         = (const int*)d_in[1];
    const float* edge_attr  = (const float*)d_in[2];
    const float* node_w     = (const float*)d_in[3];
    const float* node_b     = (const float*)d_in[4];
    const float* edge_w     = (const float*)d_in[5];
    const float* edge_b     = (const float*)d_in[6];
    const float* lin_w      = (const float*)d_in[7];
    const float* lin_edge_w = (const float*)d_in[8];
    const float* att_src    = (const float*)d_in[9];
    const float* att_dst    = (const float*)d_in[10];
    const float* att_edge   = (const float*)d_in[11];
    const float* gat_bias   = (const float*)d_in[12];
    const float* ln_g       = (const float*)d_in[13];
    const float* ln_b       = (const float*)d_in[14];

    int NN = in_sizes[0] / 8;
    int E  = in_sizes[1] / 2;
    const int* src = ei;
    const int* dst = ei + E;
    float* h = (float*)d_out;

    char* wsp = (char*)d_ws;
    size_t off = 0;
    auto alloc = [&](size_t bytes) -> void* {
        off = (off + 255) & ~(size_t)255;
        void* p = wsp + off;
        off += bytes;
        return p;
    };
    ushort* xs2     = (ushort*)alloc((size_t)NN * 64 * 2);
    float*  a_src4  = (float*)alloc((size_t)NN * 4 * 4);
    float*  a_dst4  = (float*)alloc((size_t)NN * 4 * 4);
    uint2*  recs    = (uint2*)alloc((size_t)E * 8);
    float4* ea_mean = (float4*)alloc((size_t)NN * 16);
    int*    rowptr  = (int*)alloc((size_t)(NN + 1) * 4);
    int*    degc    = (int*)alloc((size_t)NN * 4);
    int*    rank    = (int*)alloc((size_t)E * 4);
    int*    bsum    = (int*)alloc(512);
    float*  Mc      = (float*)alloc(256);

    hipMemsetAsync(degc, 0, (size_t)NN * 4, stream);
    k_smallw<<<1, 256, 0, stream>>>(lin_edge_w, att_edge, edge_w, edge_b, Mc);
    k_node_proj<<<(NN*64 + 255) / 256, 256, 0, stream>>>(x, node_w, node_b, h, NN);
    k_deg<<<2048, 256, 0, stream>>>(dst, degc, rank, E);
    int nb = (NN + 1023) / 1024;
    k_scan1<<<nb, 1024, 0, stream>>>(degc, rowptr + 1, bsum, NN);
    k_scan2<<<1, 128, 0, stream>>>(bsum, nb);
    k_scan3<<<nb, 1024, 0, stream>>>(rowptr, bsum, NN);
    k_scatter<<<2048, 256, 0, stream>>>(src, dst, rank, (const float4*)edge_attr,
                                        rowptr, recs, E);
    k_eamean<<<(NN + 255) / 256, 256, 0, stream>>>(rowptr, recs, ea_mean, NN);

    for (int l = 0; l < 3; ++l) {
        k_proj<<<2048, 256, 0, stream>>>(h, lin_w + l*4096, att_src + l*64, att_dst + l*64,
                                         xs2, a_src4, a_dst4, NN);
        k_gat<<<(NN + 3) / 4, 256, 0, stream>>>((const uint4*)xs2, a_src4, a_dst4,
                                                rowptr, recs, ea_mean,
                                                Mc + l*16, Mc + 48 + l*4,
                                                gat_bias + l*64, ln_g + l*64, ln_b + l*64,
                                                h, NN);
    }
}